// Round 5
// baseline (575.172 us; speedup 1.0000x reference)
//
#include <hip/hip_runtime.h>
#include <hip/hip_bf16.h>
#include <hip/hip_fp16.h>
#include <math.h>

// MoNet / GMMConv 2-layer GNN on MI355X (gfx950).
// R5: R4 structure with the fused2 LDS-union bug fixed: W2s (18688 B) now
// lives in a SINGLE __shared__ buffer instead of spanning two arrays whose
// adjacency the backend does not guarantee (the R4 failure corrupted As2
// rows 0-2 of every block when the arrays were reordered).

#define NF 128
#define NH 64
#define NC 16
#define NK 8
#define T1 16      // nodes per block, layer 1
#define T2 32      // nodes per block, layer 2
#define CAP1 448   // LDS edge-meta capacity, layer 1 (mean 256, +12 sigma)
#define CAP2 768   // layer 2 (mean 512, +11 sigma)

typedef __bf16 v8bf __attribute__((ext_vector_type(8)));
typedef float v4f __attribute__((ext_vector_type(4)));

__device__ inline ushort f2bu(float x) {
  __hip_bfloat16 h = __float2bfloat16(x);
  return *(ushort*)&h;
}
__device__ inline uint packh2(float a, float b) {
  __half ha = __float2half_rn(a), hb = __float2half_rn(b);
  return (uint)(*(ushort*)&ha) | ((uint)(*(ushort*)&hb) << 16);
}
__device__ inline float2 unph2(uint u) {
  ushort a = (ushort)(u & 0xffff), b = (ushort)(u >> 16);
  return make_float2(__half2float(*(__half*)&a), __half2float(*(__half*)&b));
}
__device__ inline v8bf ld_frag(const ushort* p) {
  uint4 u = *(const uint4*)p;
  return __builtin_bit_cast(v8bf, u);
}

// ---------------- CSR build ----------------
__global__ __launch_bounds__(256) void hist_kernel(const int* __restrict__ col,
                                                   int* __restrict__ counts, int E) {
  int e = blockIdx.x * 256 + threadIdx.x;
  if (e < E) atomicAdd(&counts[col[e]], 1);
}

// scan1: per-block (1024 elems) exclusive scan + block sums
__global__ __launch_bounds__(256) void scan1_kernel(const int* __restrict__ counts,
                                                    int* __restrict__ starts,
                                                    int* __restrict__ bsums) {
  __shared__ int wsum[4];
  const int t = threadIdx.x, lane = t & 63, wv = t >> 6;
  int4 v = ((const int4*)counts)[blockIdx.x * 256 + t];
  int tsum = v.x + v.y + v.z + v.w;
  int inc = tsum;
  #pragma unroll
  for (int off = 1; off < 64; off <<= 1) {
    int u = __shfl_up(inc, off, 64);
    if (lane >= off) inc += u;
  }
  if (lane == 63) wsum[wv] = inc;
  __syncthreads();
  int wpre = 0;
  for (int j = 0; j < wv; ++j) wpre += wsum[j];
  int excl = wpre + inc - tsum;
  int4 o;
  o.x = excl; o.y = o.x + v.x; o.z = o.y + v.y; o.w = o.z + v.z;
  ((int4*)starts)[blockIdx.x * 256 + t] = o;
  if (t == 255) bsums[blockIdx.x] = excl + tsum;
}

__global__ __launch_bounds__(64) void scan2_kernel(const int* __restrict__ bsums,
                                                   int* __restrict__ bofs, int NB) {
  int lane = threadIdx.x;
  int v = (lane < NB) ? bsums[lane] : 0;
  int inc = v;
  #pragma unroll
  for (int off = 1; off < 64; off <<= 1) {
    int u = __shfl_up(inc, off, 64);
    if (lane >= off) inc += u;
  }
  if (lane < NB) bofs[lane] = inc - v;
}

__global__ __launch_bounds__(256) void scan3_kernel(int* __restrict__ starts,
                                                    int* __restrict__ cursor,
                                                    const int* __restrict__ bofs) {
  int add = bofs[blockIdx.x];
  int idx = blockIdx.x * 256 + threadIdx.x;
  int4 s = ((int4*)starts)[idx];
  s.x += add; s.y += add; s.z += add; s.w += add;
  ((int4*)starts)[idx] = s;
  ((int4*)cursor)[idx] = s;
}

// ---- fill: scatter edges into CSR order; precompute fp16 gaussian w ----
__global__ __launch_bounds__(256) void fill_kernel(
    const int* __restrict__ row, const int* __restrict__ col,
    const float* __restrict__ eattr,
    const float* __restrict__ mu1, const float* __restrict__ sg1,
    const float* __restrict__ mu2, const float* __restrict__ sg2,
    int* __restrict__ cursor, int* __restrict__ erow,
    uint4* __restrict__ ew1, uint4* __restrict__ ew2, int E) {
  int e = blockIdx.x * 256 + threadIdx.x;
  if (e >= E) return;
  int c = col[e];
  int pos = atomicAdd(&cursor[c], 1);
  float p0 = eattr[2 * e], p1 = eattr[2 * e + 1];
  float w1[8], w2[8];
  #pragma unroll
  for (int k = 0; k < 8; ++k) {
    float d0 = p0 - mu1[2 * k], d1 = p1 - mu1[2 * k + 1];
    float s0 = sg1[2 * k], s1 = sg1[2 * k + 1];
    w1[k] = __expf(-0.5f * (d0 * d0 / (1e-15f + s0 * s0) +
                            d1 * d1 / (1e-15f + s1 * s1)));
    float e0 = p0 - mu2[2 * k], e1 = p1 - mu2[2 * k + 1];
    float t0 = sg2[2 * k], t1 = sg2[2 * k + 1];
    w2[k] = __expf(-0.5f * (e0 * e0 / (1e-15f + t0 * t0) +
                            e1 * e1 / (1e-15f + t1 * t1)));
  }
  erow[pos] = row[e];
  ew1[pos] = make_uint4(packh2(w1[0], w1[1]), packh2(w1[2], w1[3]),
                        packh2(w1[4], w1[5]), packh2(w1[6], w1[7]));
  ew2[pos] = make_uint4(packh2(w2[0], w2[1]), packh2(w2[2], w2[3]),
                        packh2(w2[4], w2[5]), packh2(w2[6], w2[7]));
}

// ---- cast x -> bf16 contiguous [N,128] ----
__global__ __launch_bounds__(256) void cast_x_kernel(const float* __restrict__ x,
                                                     ushort* __restrict__ xb, int N) {
  int idx = blockIdx.x * 256 + threadIdx.x;
  if (idx >= N * 32) return;
  float4 v = ((const float4*)x)[idx];
  ushort4 o;
  o.x = f2bu(v.x); o.y = f2bu(v.y); o.z = f2bu(v.z); o.w = f2bu(v.w);
  *(ushort4*)(xb + (size_t)idx * 4) = o;
}

// ---- prep: reshape+cast weights to bf16, [out][k] layout ----
// W1t[h][j] (64x1152): j<1024 -> g1w[j&127][(j>>7)*64+h]; j>=1024 -> r1w[j-1024][h]
// W2t[c][j] (16x576):  j<512  -> g2w[j&63][(j>>6)*16+c];  j>=512  -> r2w[j-512][c]
__global__ __launch_bounds__(256) void prep_kernel(
    const float* __restrict__ g1w, const float* __restrict__ r1w,
    const float* __restrict__ g2w, const float* __restrict__ r2w,
    ushort* __restrict__ W1t, ushort* __restrict__ W2t) {
  int i = blockIdx.x * 256 + threadIdx.x;
  if (i < 64 * 1152) {
    int h = i / 1152, j = i % 1152;
    float v = (j < 1024) ? g1w[(size_t)(j & 127) * 512 + (j >> 7) * 64 + h]
                         : r1w[(size_t)(j - 1024) * 64 + h];
    W1t[i] = f2bu(v);
  } else {
    int i2 = i - 64 * 1152;
    if (i2 < 16 * 576) {
      int c = i2 / 576, j = i2 % 576;
      float v = (j < 512) ? g2w[(size_t)(j & 63) * 128 + (j >> 6) * 16 + c]
                          : r2w[(size_t)(j - 512) * 16 + c];
      W2t[i2] = f2bu(v);
    }
  }
}

// ================= fused layer 1 =================
// 16 nodes/block. Phase A: gather Z -> LDS A-tile [16 x 1152+pad].
// Phase B: (16x1152)@(1152x64) bf16 MFMA, ELU epilogue -> h_bf.
#define AS1 1160   // 1152 + 8 pad
__global__ __launch_bounds__(256, 3) void fused1_kernel(
    const ushort* __restrict__ x_bf, const int* __restrict__ erow,
    const uint4* __restrict__ ew1, const int* __restrict__ starts,
    const ushort* __restrict__ W1t, const float* __restrict__ b1,
    ushort* __restrict__ h_bf, int N) {
  __shared__ ushort As[T1 * AS1];                // 37120 B
  __shared__ __align__(16) char UN[CAP1 * 20];   // 8960 B: meta / Ws union
  uint4* lw = (uint4*)UN;                        // CAP1*16 = 7168 B
  int* lrow = (int*)(UN + CAP1 * 16);            // CAP1*4  = 1792 B
  ushort* Ws = (ushort*)UN;                      // phase B: 64x40 = 5120 B (fits)

  const int t = threadIdx.x, lane = t & 63, wv = t >> 6;
  const int base = (int)blockIdx.x * T1;
  const int S = starts[base];
  const int S2 = starts[base + T1];
  const int cl = min(S2 - S, CAP1);
  for (int i = t; i < cl; i += 256) {
    lrow[i] = erow[S + i];
    lw[i] = ew1[S + i];
  }
  __syncthreads();

  const int mfrag = lane & 15, quad = lane >> 4;

#define MROW1(j) (((j) - S < cl) ? lrow[(j) - S] : erow[(j)])
#define MW1(j)   (((j) - S < cl) ? lw[(j) - S]   : ew1[(j)])
  for (int i = 0; i < T1 / 4; ++i) {
    const int nn = wv * 4 + i;
    const int n = base + nn;
    float acc[8][2];
    #pragma unroll
    for (int k = 0; k < 8; ++k) { acc[k][0] = 0.f; acc[k][1] = 0.f; }
    const int be = starts[n], ee = starts[n + 1];
    if (be < ee) {
      int j1 = min(be + 1, ee - 1);
      int rA = MROW1(be), rB = MROW1(j1);
      uint xA = *(const uint*)(x_bf + (size_t)rA * NF + 2 * lane);
      uint xB = *(const uint*)(x_bf + (size_t)rB * NF + 2 * lane);
      for (int j = be; j < ee; ++j) {
        int jn = min(j + 2, ee - 1);
        int rC = MROW1(jn);
        uint xC = *(const uint*)(x_bf + (size_t)rC * NF + 2 * lane);
        uint4 wq = MW1(j);
        float2 w01 = unph2(wq.x), w23 = unph2(wq.y);
        float2 w45 = unph2(wq.z), w67 = unph2(wq.w);
        float f0 = __uint_as_float(xA << 16);
        float f1 = __uint_as_float(xA & 0xffff0000u);
        acc[0][0] = fmaf(w01.x, f0, acc[0][0]); acc[0][1] = fmaf(w01.x, f1, acc[0][1]);
        acc[1][0] = fmaf(w01.y, f0, acc[1][0]); acc[1][1] = fmaf(w01.y, f1, acc[1][1]);
        acc[2][0] = fmaf(w23.x, f0, acc[2][0]); acc[2][1] = fmaf(w23.x, f1, acc[2][1]);
        acc[3][0] = fmaf(w23.y, f0, acc[3][0]); acc[3][1] = fmaf(w23.y, f1, acc[3][1]);
        acc[4][0] = fmaf(w45.x, f0, acc[4][0]); acc[4][1] = fmaf(w45.x, f1, acc[4][1]);
        acc[5][0] = fmaf(w45.y, f0, acc[5][0]); acc[5][1] = fmaf(w45.y, f1, acc[5][1]);
        acc[6][0] = fmaf(w67.x, f0, acc[6][0]); acc[6][1] = fmaf(w67.x, f1, acc[6][1]);
        acc[7][0] = fmaf(w67.y, f0, acc[7][0]); acc[7][1] = fmaf(w67.y, f1, acc[7][1]);
        xA = xB; xB = xC;
      }
    }
    const float inv = 1.f / fmaxf((float)(ee - be), 1.f);
    #pragma unroll
    for (int k = 0; k < 8; ++k) {
      uint pk = (uint)f2bu(acc[k][0] * inv) | ((uint)f2bu(acc[k][1] * inv) << 16);
      *(uint*)(As + nn * AS1 + k * 128 + 2 * lane) = pk;
    }
    uint xs = 0;
    if (n < N) xs = *(const uint*)(x_bf + (size_t)n * NF + 2 * lane);
    *(uint*)(As + nn * AS1 + 1024 + 2 * lane) = xs;
  }
#undef MROW1
#undef MW1

  // Phase B: M=16, N=64 (wave wv owns col-tile wv), K=1152 (36 chunks)
  v4f cacc = (v4f){0.f, 0.f, 0.f, 0.f};
  for (int kc = 0; kc < 36; ++kc) {
    __syncthreads();                 // protect Ws (and meta/As on kc==0)
    {
      int rw_ = t >> 2, ko = (t & 3) * 8;
      uint4 u = *(const uint4*)(W1t + (size_t)rw_ * 1152 + kc * 32 + ko);
      *(uint4*)(Ws + rw_ * 40 + ko) = u;
    }
    __syncthreads();
    v8bf a = ld_frag(As + mfrag * AS1 + kc * 32 + quad * 8);
    v8bf bb = ld_frag(Ws + (wv * 16 + mfrag) * 40 + quad * 8);
    cacc = __builtin_amdgcn_mfma_f32_16x16x32_bf16(a, bb, cacc, 0, 0, 0);
  }
  const int colh = wv * 16 + mfrag;
  const float bc = b1[colh];
  #pragma unroll
  for (int r = 0; r < 4; ++r) {
    int node = base + quad * 4 + r;
    if (node < N) {
      float v = cacc[r] + bc;
      v = v > 0.f ? v : expm1f(v);
      h_bf[(size_t)node * NH + colh] = f2bu(v);
    }
  }
}

// ================= fused layer 2 =================
// 32 nodes/block. Phase A: gather Z2 -> LDS [32 x 512+64+pad].
// Phase B: (32x576)@(576x16) bf16 MFMA, log_softmax epilogue -> out.
#define AS2 584    // 576 + 8 pad
#define UN2SZ (16 * AS2 * 2)   // 18688 B: W2s needs the max; meta (15360) fits
__global__ __launch_bounds__(256, 2) void fused2_kernel(
    const ushort* __restrict__ h_bf, const int* __restrict__ erow,
    const uint4* __restrict__ ew2, const int* __restrict__ starts,
    const ushort* __restrict__ W2t, const float* __restrict__ b2,
    float* __restrict__ out, int N) {
  __shared__ ushort As2[T2 * AS2];               // 37376 B
  __shared__ __align__(16) char UN[UN2SZ];       // 18688 B single union buffer
  uint4* lw = (uint4*)UN;                        // CAP2*16 = 12288 B
  int* lrow = (int*)(UN + CAP2 * 16);            // CAP2*4  = 3072 B -> 15360
  ushort* W2s = (ushort*)UN;                     // phase B: 16 x 584 = 18688 B

  const int t = threadIdx.x, lane = t & 63, wv = t >> 6;
  const int base = (int)blockIdx.x * T2;
  const int S = starts[base];
  const int S2 = starts[base + T2];
  const int cl = min(S2 - S, CAP2);
  for (int i = t; i < cl; i += 256) {
    lrow[i] = erow[S + i];
    lw[i] = ew2[S + i];
  }
  __syncthreads();

  const int mfrag = lane & 15, quad = lane >> 4;

#define MROW2(j) (((j) - S < cl) ? lrow[(j) - S] : erow[(j)])
#define MW2(j)   (((j) - S < cl) ? lw[(j) - S]   : ew2[(j)])
  for (int i = 0; i < T2 / 4; ++i) {
    const int nn = wv * 8 + i;
    const int n = base + nn;
    float acc[8];
    #pragma unroll
    for (int k = 0; k < 8; ++k) acc[k] = 0.f;
    const int be = starts[n], ee = starts[n + 1];
    if (be < ee) {
      int j1 = min(be + 1, ee - 1);
      int rA = MROW2(be), rB = MROW2(j1);
      ushort xA = h_bf[(size_t)rA * NH + lane];
      ushort xB = h_bf[(size_t)rB * NH + lane];
      for (int j = be; j < ee; ++j) {
        int jn = min(j + 2, ee - 1);
        int rC = MROW2(jn);
        ushort xC = h_bf[(size_t)rC * NH + lane];
        uint4 wq = MW2(j);
        float2 w01 = unph2(wq.x), w23 = unph2(wq.y);
        float2 w45 = unph2(wq.z), w67 = unph2(wq.w);
        float f = __uint_as_float(((uint)xA) << 16);
        acc[0] = fmaf(w01.x, f, acc[0]); acc[1] = fmaf(w01.y, f, acc[1]);
        acc[2] = fmaf(w23.x, f, acc[2]); acc[3] = fmaf(w23.y, f, acc[3]);
        acc[4] = fmaf(w45.x, f, acc[4]); acc[5] = fmaf(w45.y, f, acc[5]);
        acc[6] = fmaf(w67.x, f, acc[6]); acc[7] = fmaf(w67.y, f, acc[7]);
        xA = xB; xB = xC;
      }
    }
    const float inv = 1.f / fmaxf((float)(ee - be), 1.f);
    #pragma unroll
    for (int k = 0; k < 8; ++k)
      As2[nn * AS2 + k * 64 + lane] = f2bu(acc[k] * inv);
    ushort hs = 0;
    if (n < N) hs = h_bf[(size_t)n * NH + lane];
    As2[nn * AS2 + 512 + lane] = hs;
  }
#undef MROW2
#undef MW2

  __syncthreads();
  // preload W2t fully into LDS (overwrites meta; phase A done for all waves)
  for (int i2 = t; i2 < 1152; i2 += 256) {       // 16*576/8 uint4s
    int rr = i2 / 72, jj = (i2 % 72) * 8;
    uint4 u = *(const uint4*)(W2t + (size_t)rr * 576 + jj);
    *(uint4*)(W2s + rr * AS2 + jj) = u;
  }
  __syncthreads();
  if (wv >= 2) return;   // 2 waves cover the 2 M-tiles; no barriers after

  v4f cacc = (v4f){0.f, 0.f, 0.f, 0.f};
  for (int kc = 0; kc < 18; ++kc) {
    v8bf a = ld_frag(As2 + (wv * 16 + mfrag) * AS2 + kc * 32 + quad * 8);
    v8bf bb = ld_frag(W2s + mfrag * AS2 + kc * 32 + quad * 8);
    cacc = __builtin_amdgcn_mfma_f32_16x16x32_bf16(a, bb, cacc, 0, 0, 0);
  }
  const float bc = b2[mfrag];
  #pragma unroll
  for (int r = 0; r < 4; ++r) {
    int node = base + wv * 16 + quad * 4 + r;
    float v = cacc[r] + bc;
    float mx = v;
    #pragma unroll
    for (int off = 8; off >= 1; off >>= 1) mx = fmaxf(mx, __shfl_xor(mx, off, 64));
    float sm = __expf(v - mx);
    #pragma unroll
    for (int off = 8; off >= 1; off >>= 1) sm += __shfl_xor(sm, off, 64);
    if (node < N) out[(size_t)node * NC + mfrag] = v - mx - __logf(sm);
  }
}

extern "C" void kernel_launch(void* const* d_in, const int* in_sizes, int n_in,
                              void* d_out, int out_size, void* d_ws, size_t ws_size,
                              hipStream_t stream) {
  const float* x     = (const float*)d_in[0];
  const int*   eidx  = (const int*)d_in[1];
  const float* eattr = (const float*)d_in[2];
  const float* g1w   = (const float*)d_in[3];
  const float* mu1   = (const float*)d_in[4];
  const float* sg1   = (const float*)d_in[5];
  const float* r1w   = (const float*)d_in[6];
  const float* b1    = (const float*)d_in[7];
  const float* g2w   = (const float*)d_in[8];
  const float* mu2   = (const float*)d_in[9];
  const float* sg2   = (const float*)d_in[10];
  const float* r2w   = (const float*)d_in[11];
  const float* b2    = (const float*)d_in[12];

  const int N = in_sizes[0] / NF;        // 50000
  const int E = in_sizes[1] / 2;         // 800000
  const int* row = eidx;
  const int* col = eidx + E;
  const int NP = (N + 1023) & ~1023;     // 50176
  const int NB = NP / 1024;              // 49

  // Workspace layout (16B-aligned chunks first):
  uint4* ew1   = (uint4*)d_ws;                         // E
  uint4* ew2   = ew1 + (size_t)E;                      // E
  ushort* x_bf = (ushort*)(ew2 + (size_t)E);           // N*128
  ushort* h_bf = x_bf + (size_t)N * NF;                // N*64
  ushort* W1t  = h_bf + (size_t)N * NH;                // 64*1152
  ushort* W2t  = W1t + (size_t)64 * 1152;              // 16*576
  int* erow    = (int*)(W2t + (size_t)16 * 576);       // E
  int* counts  = erow + (size_t)E;                     // NP
  int* starts  = counts + NP;                          // NP
  int* cursor  = starts + NP;                          // NP
  int* bsums   = cursor + NP;                          // NB
  int* bofs    = bsums + 64;                           // NB

  hipMemsetAsync(counts, 0, (size_t)NP * sizeof(int), stream);
  hist_kernel<<<(E + 255) / 256, 256, 0, stream>>>(col, counts, E);
  scan1_kernel<<<NB, 256, 0, stream>>>(counts, starts, bsums);
  scan2_kernel<<<1, 64, 0, stream>>>(bsums, bofs, NB);
  scan3_kernel<<<NB, 256, 0, stream>>>(starts, cursor, bofs);
  fill_kernel<<<(E + 255) / 256, 256, 0, stream>>>(row, col, eattr, mu1, sg1,
                                                   mu2, sg2, cursor, erow,
                                                   ew1, ew2, E);
  cast_x_kernel<<<(N * 32 + 255) / 256, 256, 0, stream>>>(x, x_bf, N);
  prep_kernel<<<(64 * 1152 + 16 * 576 + 255) / 256, 256, 0, stream>>>(
      g1w, r1w, g2w, r2w, W1t, W2t);

  fused1_kernel<<<(N + T1 - 1) / T1, 256, 0, stream>>>(x_bf, erow, ew1, starts,
                                                       W1t, b1, h_bf, N);
  fused2_kernel<<<(N + T2 - 1) / T2, 256, 0, stream>>>(h_bf, erow, ew2, starts,
                                                       W2t, b2, (float*)d_out, N);
}

// Round 6
// 435.916 us; speedup vs baseline: 1.3195x; 1.3195x over previous
//
#include <hip/hip_runtime.h>
#include <hip/hip_bf16.h>
#include <hip/hip_fp16.h>
#include <math.h>

// MoNet / GMMConv 2-layer GNN on MI355X (gfx950).
// R6: unfused Z-kernels (high occupancy, tiny LDS) + LDS-free MFMA GEMMs.
// Lesson from R5: gather is latency-bound -> needs waves, not LDS tiles.
// z kernels: edge meta staged in LDS as fp32 (no exp/shuffle/unpack in hot
// loop), x-gather pipelined 2-deep. GEMMs read A/B fragments directly from
// global (L2/L3-warm), no barriers. Z2 aliases A1 (dead after gemm1).

#define NF 128
#define NH 64
#define NC 16
#define Z1NODES 16
#define Z1CAP 448    // Poisson(256) +12sd; overflow -> global fallback (correct)
#define Z2NODES 32
#define Z2CAP 576    // Poisson(512) +2.8sd; overflow -> global fallback

typedef __bf16 v8bf __attribute__((ext_vector_type(8)));
typedef float v4f __attribute__((ext_vector_type(4)));

__device__ inline ushort f2bu(float x) {
  __hip_bfloat16 h = __float2bfloat16(x);
  return *(ushort*)&h;
}
__device__ inline uint packh2(float a, float b) {
  __half ha = __float2half_rn(a), hb = __float2half_rn(b);
  return (uint)(*(ushort*)&ha) | ((uint)(*(ushort*)&hb) << 16);
}
__device__ inline float2 unph2(uint u) {
  ushort a = (ushort)(u & 0xffff), b = (ushort)(u >> 16);
  return make_float2(__half2float(*(__half*)&a), __half2float(*(__half*)&b));
}
__device__ inline v8bf ld_frag(const ushort* p) {
  uint4 u = *(const uint4*)p;
  return __builtin_bit_cast(v8bf, u);
}

// ---------------- CSR build (verified R5) ----------------
__global__ __launch_bounds__(256) void hist_kernel(const int* __restrict__ col,
                                                   int* __restrict__ counts, int E) {
  int e = blockIdx.x * 256 + threadIdx.x;
  if (e < E) atomicAdd(&counts[col[e]], 1);
}

__global__ __launch_bounds__(256) void scan1_kernel(const int* __restrict__ counts,
                                                    int* __restrict__ starts,
                                                    int* __restrict__ bsums) {
  __shared__ int wsum[4];
  const int t = threadIdx.x, lane = t & 63, wv = t >> 6;
  int4 v = ((const int4*)counts)[blockIdx.x * 256 + t];
  int tsum = v.x + v.y + v.z + v.w;
  int inc = tsum;
  #pragma unroll
  for (int off = 1; off < 64; off <<= 1) {
    int u = __shfl_up(inc, off, 64);
    if (lane >= off) inc += u;
  }
  if (lane == 63) wsum[wv] = inc;
  __syncthreads();
  int wpre = 0;
  for (int j = 0; j < wv; ++j) wpre += wsum[j];
  int excl = wpre + inc - tsum;
  int4 o;
  o.x = excl; o.y = o.x + v.x; o.z = o.y + v.y; o.w = o.z + v.z;
  ((int4*)starts)[blockIdx.x * 256 + t] = o;
  if (t == 255) bsums[blockIdx.x] = excl + tsum;
}

__global__ __launch_bounds__(64) void scan2_kernel(const int* __restrict__ bsums,
                                                   int* __restrict__ bofs, int NB) {
  int lane = threadIdx.x;
  int v = (lane < NB) ? bsums[lane] : 0;
  int inc = v;
  #pragma unroll
  for (int off = 1; off < 64; off <<= 1) {
    int u = __shfl_up(inc, off, 64);
    if (lane >= off) inc += u;
  }
  if (lane < NB) bofs[lane] = inc - v;
}

__global__ __launch_bounds__(256) void scan3_kernel(int* __restrict__ starts,
                                                    int* __restrict__ cursor,
                                                    const int* __restrict__ bofs) {
  int add = bofs[blockIdx.x];
  int idx = blockIdx.x * 256 + threadIdx.x;
  int4 s = ((int4*)starts)[idx];
  s.x += add; s.y += add; s.z += add; s.w += add;
  ((int4*)starts)[idx] = s;
  ((int4*)cursor)[idx] = s;
}

__global__ __launch_bounds__(256) void fill_kernel(
    const int* __restrict__ row, const int* __restrict__ col,
    const float* __restrict__ eattr,
    const float* __restrict__ mu1, const float* __restrict__ sg1,
    const float* __restrict__ mu2, const float* __restrict__ sg2,
    int* __restrict__ cursor, int* __restrict__ erow,
    uint4* __restrict__ ew1, uint4* __restrict__ ew2, int E) {
  int e = blockIdx.x * 256 + threadIdx.x;
  if (e >= E) return;
  int c = col[e];
  int pos = atomicAdd(&cursor[c], 1);
  float p0 = eattr[2 * e], p1 = eattr[2 * e + 1];
  float w1[8], w2[8];
  #pragma unroll
  for (int k = 0; k < 8; ++k) {
    float d0 = p0 - mu1[2 * k], d1 = p1 - mu1[2 * k + 1];
    float s0 = sg1[2 * k], s1 = sg1[2 * k + 1];
    w1[k] = __expf(-0.5f * (d0 * d0 / (1e-15f + s0 * s0) +
                            d1 * d1 / (1e-15f + s1 * s1)));
    float e0 = p0 - mu2[2 * k], e1 = p1 - mu2[2 * k + 1];
    float t0 = sg2[2 * k], t1 = sg2[2 * k + 1];
    w2[k] = __expf(-0.5f * (e0 * e0 / (1e-15f + t0 * t0) +
                            e1 * e1 / (1e-15f + t1 * t1)));
  }
  erow[pos] = row[e];
  ew1[pos] = make_uint4(packh2(w1[0], w1[1]), packh2(w1[2], w1[3]),
                        packh2(w1[4], w1[5]), packh2(w1[6], w1[7]));
  ew2[pos] = make_uint4(packh2(w2[0], w2[1]), packh2(w2[2], w2[3]),
                        packh2(w2[4], w2[5]), packh2(w2[6], w2[7]));
}

// ---- cast x -> bf16 into A1 columns [1024..1151] (row stride 1152) ----
__global__ __launch_bounds__(256) void cast_x_kernel(const float* __restrict__ x,
                                                     ushort* __restrict__ A1, int N) {
  int idx = blockIdx.x * 256 + threadIdx.x;
  if (idx >= N * 32) return;
  int n = idx >> 5, c4 = idx & 31;
  float4 v = ((const float4*)x)[idx];
  ushort4 o;
  o.x = f2bu(v.x); o.y = f2bu(v.y); o.z = f2bu(v.z); o.w = f2bu(v.w);
  *(ushort4*)(A1 + (size_t)n * 1152 + 1024 + c4 * 4) = o;
}

// ---- prep: reshape+cast weights to bf16, [out][k] layout (verified R3/R5) ----
__global__ __launch_bounds__(256) void prep_kernel(
    const float* __restrict__ g1w, const float* __restrict__ r1w,
    const float* __restrict__ g2w, const float* __restrict__ r2w,
    ushort* __restrict__ W1t, ushort* __restrict__ W2t) {
  int i = blockIdx.x * 256 + threadIdx.x;
  if (i < 64 * 1152) {
    int h = i / 1152, j = i % 1152;
    float v = (j < 1024) ? g1w[(size_t)(j & 127) * 512 + (j >> 7) * 64 + h]
                         : r1w[(size_t)(j - 1024) * 64 + h];
    W1t[i] = f2bu(v);
  } else {
    int i2 = i - 64 * 1152;
    if (i2 < 16 * 576) {
      int c = i2 / 576, j = i2 % 576;
      float v = (j < 512) ? g2w[(size_t)(j & 63) * 128 + (j >> 6) * 16 + c]
                          : r2w[(size_t)(j - 512) * 16 + c];
      W2t[i2] = f2bu(v);
    }
  }
}

// ======= z1: Z[n, k*128+f] = (1/deg) sum_e w_ek * x_bf[r_e, f] =======
// 16 nodes/block (4/wave). Meta staged in LDS as fp32. x pipelined 2-deep.
__global__ __launch_bounds__(256) void z1_kernel(
    ushort* __restrict__ A1, const int* __restrict__ erow,
    const uint4* __restrict__ ew1, const int* __restrict__ starts, int N) {
  __shared__ float lw[Z1CAP][8];    // 14336 B
  __shared__ int lrow[Z1CAP];       //  1792 B
  const int t = threadIdx.x, lane = t & 63, wv = t >> 6;
  const int base = (int)blockIdx.x * Z1NODES;
  const int S = starts[base];
  const int cl = min(starts[base + Z1NODES] - S, Z1CAP);
  for (int i = t; i < cl; i += 256) {
    lrow[i] = erow[S + i];
    uint4 q = ew1[S + i];
    float2 a = unph2(q.x), b = unph2(q.y), c = unph2(q.z), d = unph2(q.w);
    *(float4*)&lw[i][0] = make_float4(a.x, a.y, b.x, b.y);
    *(float4*)&lw[i][4] = make_float4(c.x, c.y, d.x, d.y);
  }
  __syncthreads();

  for (int i = 0; i < Z1NODES / 4; ++i) {
    const int n = base + wv * 4 + i;
    const int be = starts[n], ee = starts[n + 1];
    float a0[8], a1[8];
    #pragma unroll
    for (int k = 0; k < 8; ++k) { a0[k] = 0.f; a1[k] = 0.f; }
    if (be < ee) {
      auto ROW = [&](int j) -> int {
        int rel = j - S;
        return (rel < cl) ? lrow[rel] : erow[j];
      };
      int r0 = ROW(be);
      int j1 = min(be + 1, ee - 1);
      int r1 = ROW(j1);
      uint x0 = *(const uint*)(A1 + (size_t)r0 * 1152 + 1024 + 2 * lane);
      uint x1 = *(const uint*)(A1 + (size_t)r1 * 1152 + 1024 + 2 * lane);
      for (int j = be; j < ee; ++j) {
        int jn = min(j + 2, ee - 1);
        int rn = ROW(jn);
        uint xn = *(const uint*)(A1 + (size_t)rn * 1152 + 1024 + 2 * lane);
        float w8[8];
        int rel = j - S;
        if (rel < cl) {
          float4 lo = *(const float4*)&lw[rel][0];
          float4 hi = *(const float4*)&lw[rel][4];
          w8[0] = lo.x; w8[1] = lo.y; w8[2] = lo.z; w8[3] = lo.w;
          w8[4] = hi.x; w8[5] = hi.y; w8[6] = hi.z; w8[7] = hi.w;
        } else {
          uint4 q = ew1[j];
          float2 a = unph2(q.x), b = unph2(q.y), c = unph2(q.z), d = unph2(q.w);
          w8[0] = a.x; w8[1] = a.y; w8[2] = b.x; w8[3] = b.y;
          w8[4] = c.x; w8[5] = c.y; w8[6] = d.x; w8[7] = d.y;
        }
        float f0 = __uint_as_float(x0 << 16);
        float f1 = __uint_as_float(x0 & 0xffff0000u);
        #pragma unroll
        for (int k = 0; k < 8; ++k) {
          a0[k] = fmaf(w8[k], f0, a0[k]);
          a1[k] = fmaf(w8[k], f1, a1[k]);
        }
        x0 = x1; x1 = xn;
      }
    }
    const float inv = 1.f / fmaxf((float)(ee - be), 1.f);
    ushort* zr = A1 + (size_t)n * 1152;
    #pragma unroll
    for (int k = 0; k < 8; ++k) {
      uint pk = (uint)f2bu(a0[k] * inv) | ((uint)f2bu(a1[k] * inv) << 16);
      *(uint*)(zr + k * 128 + 2 * lane) = pk;
    }
  }
}

// ---- gemm1: h_bf = ELU( A1[N2,1152] @ W1t^T + b1 ), LDS-free MFMA ----
__global__ __launch_bounds__(256) void gemm1_mfma(
    const ushort* __restrict__ A1, const ushort* __restrict__ W1t,
    const float* __restrict__ b1, ushort* __restrict__ h_bf, int N) {
  const int t = threadIdx.x, lane = t & 63, wv = t >> 6;
  const int mfrag = lane & 15, quad = lane >> 4;
  const int m0 = (int)blockIdx.x * 64 + wv * 16;
  v4f acc[4];
  #pragma unroll
  for (int ct = 0; ct < 4; ++ct) acc[ct] = (v4f){0.f, 0.f, 0.f, 0.f};
  const ushort* arow = A1 + (size_t)(m0 + mfrag) * 1152 + quad * 8;
  const ushort* brow = W1t + (size_t)mfrag * 1152 + quad * 8;
  for (int kc = 0; kc < 36; ++kc) {
    v8bf a = ld_frag(arow + kc * 32);
    #pragma unroll
    for (int ct = 0; ct < 4; ++ct) {
      v8bf b = ld_frag(brow + (size_t)ct * 16 * 1152 + kc * 32);
      acc[ct] = __builtin_amdgcn_mfma_f32_16x16x32_bf16(a, b, acc[ct], 0, 0, 0);
    }
  }
  #pragma unroll
  for (int ct = 0; ct < 4; ++ct) {
    const int colh = ct * 16 + mfrag;
    const float bc = b1[colh];
    #pragma unroll
    for (int r = 0; r < 4; ++r) {
      int node = m0 + quad * 4 + r;
      if (node < N) {
        float v = acc[ct][r] + bc;
        v = v > 0.f ? v : expm1f(v);
        h_bf[(size_t)node * NH + colh] = f2bu(v);
      }
    }
  }
}

// ======= z2: Z2[n, k*64+f] = (1/deg) sum_e w_ek * h_bf[r_e, f] =======
// 32 nodes/block (8/wave). Z2 aliases A1 (row stride 512).
__global__ __launch_bounds__(256) void z2_kernel(
    const ushort* __restrict__ h_bf, ushort* __restrict__ Z2,
    const int* __restrict__ erow, const uint4* __restrict__ ew2,
    const int* __restrict__ starts, int N) {
  __shared__ float lw[Z2CAP][8];    // 18432 B
  __shared__ int lrow[Z2CAP];       //  2304 B
  const int t = threadIdx.x, lane = t & 63, wv = t >> 6;
  const int base = (int)blockIdx.x * Z2NODES;
  const int S = starts[base];
  const int cl = min(starts[base + Z2NODES] - S, Z2CAP);
  for (int i = t; i < cl; i += 256) {
    lrow[i] = erow[S + i];
    uint4 q = ew2[S + i];
    float2 a = unph2(q.x), b = unph2(q.y), c = unph2(q.z), d = unph2(q.w);
    *(float4*)&lw[i][0] = make_float4(a.x, a.y, b.x, b.y);
    *(float4*)&lw[i][4] = make_float4(c.x, c.y, d.x, d.y);
  }
  __syncthreads();

  for (int i = 0; i < Z2NODES / 4; ++i) {
    const int n = base + wv * 8 + i;
    if (n >= N) continue;
    const int be = starts[n], ee = starts[n + 1];
    float acc[8];
    #pragma unroll
    for (int k = 0; k < 8; ++k) acc[k] = 0.f;
    if (be < ee) {
      auto ROW = [&](int j) -> int {
        int rel = j - S;
        return (rel < cl) ? lrow[rel] : erow[j];
      };
      int r0 = ROW(be);
      int j1 = min(be + 1, ee - 1);
      int r1 = ROW(j1);
      ushort x0 = h_bf[(size_t)r0 * NH + lane];
      ushort x1 = h_bf[(size_t)r1 * NH + lane];
      for (int j = be; j < ee; ++j) {
        int jn = min(j + 2, ee - 1);
        int rn = ROW(jn);
        ushort xn = h_bf[(size_t)rn * NH + lane];
        float w8[8];
        int rel = j - S;
        if (rel < cl) {
          float4 lo = *(const float4*)&lw[rel][0];
          float4 hi = *(const float4*)&lw[rel][4];
          w8[0] = lo.x; w8[1] = lo.y; w8[2] = lo.z; w8[3] = lo.w;
          w8[4] = hi.x; w8[5] = hi.y; w8[6] = hi.z; w8[7] = hi.w;
        } else {
          uint4 q = ew2[j];
          float2 a = unph2(q.x), b = unph2(q.y), c = unph2(q.z), d = unph2(q.w);
          w8[0] = a.x; w8[1] = a.y; w8[2] = b.x; w8[3] = b.y;
          w8[4] = c.x; w8[5] = c.y; w8[6] = d.x; w8[7] = d.y;
        }
        float f = __uint_as_float(((uint)x0) << 16);
        #pragma unroll
        for (int k = 0; k < 8; ++k) acc[k] = fmaf(w8[k], f, acc[k]);
        x0 = x1; x1 = xn;
      }
    }
    const float inv = 1.f / fmaxf((float)(ee - be), 1.f);
    ushort* zr = Z2 + (size_t)n * 512;
    #pragma unroll
    for (int k = 0; k < 8; ++k) zr[k * 64 + lane] = f2bu(acc[k] * inv);
  }
}

// ---- gemm2: out = log_softmax( [Z2 | h_bf] @ W2t^T + b2 ), LDS-free ----
__global__ __launch_bounds__(256) void gemm2_mfma(
    const ushort* __restrict__ Z2, const ushort* __restrict__ h_bf,
    const ushort* __restrict__ W2t, const float* __restrict__ b2,
    float* __restrict__ out, int N) {
  const int t = threadIdx.x, lane = t & 63, wv = t >> 6;
  const int mfrag = lane & 15, quad = lane >> 4;
  const int m0 = (int)blockIdx.x * 64 + wv * 16;
  v4f acc = (v4f){0.f, 0.f, 0.f, 0.f};
  const ushort* arow = Z2 + (size_t)(m0 + mfrag) * 512 + quad * 8;
  const ushort* hrow = h_bf + (size_t)(m0 + mfrag) * 64 + quad * 8;
  const ushort* brow = W2t + (size_t)mfrag * 576 + quad * 8;
  for (int kc = 0; kc < 16; ++kc) {
    v8bf a = ld_frag(arow + kc * 32);
    v8bf b = ld_frag(brow + kc * 32);
    acc = __builtin_amdgcn_mfma_f32_16x16x32_bf16(a, b, acc, 0, 0, 0);
  }
  #pragma unroll
  for (int kc = 16; kc < 18; ++kc) {
    v8bf a = ld_frag(hrow + (kc - 16) * 32);
    v8bf b = ld_frag(brow + kc * 32);
    acc = __builtin_amdgcn_mfma_f32_16x16x32_bf16(a, b, acc, 0, 0, 0);
  }
  const float bc = b2[mfrag];
  #pragma unroll
  for (int r = 0; r < 4; ++r) {
    int node = m0 + quad * 4 + r;
    float v = acc[r] + bc;
    float mx = v;
    #pragma unroll
    for (int off = 8; off >= 1; off >>= 1) mx = fmaxf(mx, __shfl_xor(mx, off, 64));
    float sm = __expf(v - mx);
    #pragma unroll
    for (int off = 8; off >= 1; off >>= 1) sm += __shfl_xor(sm, off, 64);
    if (node < N) out[(size_t)node * NC + mfrag] = v - mx - __logf(sm);
  }
}

extern "C" void kernel_launch(void* const* d_in, const int* in_sizes, int n_in,
                              void* d_out, int out_size, void* d_ws, size_t ws_size,
                              hipStream_t stream) {
  const float* x     = (const float*)d_in[0];
  const int*   eidx  = (const int*)d_in[1];
  const float* eattr = (const float*)d_in[2];
  const float* g1w   = (const float*)d_in[3];
  const float* mu1   = (const float*)d_in[4];
  const float* sg1   = (const float*)d_in[5];
  const float* r1w   = (const float*)d_in[6];
  const float* b1    = (const float*)d_in[7];
  const float* g2w   = (const float*)d_in[8];
  const float* mu2   = (const float*)d_in[9];
  const float* sg2   = (const float*)d_in[10];
  const float* r2w   = (const float*)d_in[11];
  const float* b2    = (const float*)d_in[12];

  const int N = in_sizes[0] / NF;        // 50000
  const int E = in_sizes[1] / 2;         // 800000
  const int* row = eidx;
  const int* col = eidx + E;
  const int N2 = (N + 63) & ~63;         // 50048
  const int NP = (N + 1023) & ~1023;     // 50176
  const int NB = NP / 1024;              // 49

  // Workspace (~151 MB):
  uint4* ew1   = (uint4*)d_ws;                         // E
  uint4* ew2   = ew1 + (size_t)E;                      // E
  ushort* A1   = (ushort*)(ew2 + (size_t)E);           // N2*1152 (Z1|x); Z2 aliases
  ushort* Z2   = A1;                                   // [N2,512] after gemm1
  ushort* h_bf = A1 + (size_t)N2 * 1152;               // N2*64
  ushort* W1t  = h_bf + (size_t)N2 * NH;               // 64*1152
  ushort* W2t  = W1t + (size_t)64 * 1152;              // 16*576
  int* erow    = (int*)(W2t + (size_t)16 * 576);       // E
  int* counts  = erow + (size_t)E;                     // NP
  int* starts  = counts + NP;                          // NP
  int* cursor  = starts + NP;                          // NP
  int* bsums   = cursor + NP;                          // 64
  int* bofs    = bsums + 64;                           // 64

  hipMemsetAsync(counts, 0, (size_t)NP * sizeof(int), stream);
  hist_kernel<<<(E + 255) / 256, 256, 0, stream>>>(col, counts, E);
  scan1_kernel<<<NB, 256, 0, stream>>>(counts, starts, bsums);
  scan2_kernel<<<1, 64, 0, stream>>>(bsums, bofs, NB);
  scan3_kernel<<<NB, 256, 0, stream>>>(starts, cursor, bofs);
  fill_kernel<<<(E + 255) / 256, 256, 0, stream>>>(row, col, eattr, mu1, sg1,
                                                   mu2, sg2, cursor, erow,
                                                   ew1, ew2, E);
  cast_x_kernel<<<(N * 32 + 255) / 256, 256, 0, stream>>>(x, A1, N);
  prep_kernel<<<(64 * 1152 + 16 * 576 + 255) / 256, 256, 0, stream>>>(
      g1w, r1w, g2w, r2w, W1t, W2t);

  z1_kernel<<<N / Z1NODES, 256, 0, stream>>>(A1, erow, ew1, starts, N);
  gemm1_mfma<<<N2 / 64, 256, 0, stream>>>(A1, W1t, b1, h_bf, N);
  z2_kernel<<<(N + Z2NODES - 1) / Z2NODES, 256, 0, stream>>>(h_bf, Z2, erow,
                                                             ew2, starts, N);
  gemm2_mfma<<<N2 / 64, 256, 0, stream>>>(Z2, h_bf, W2t, b2, (float*)d_out, N);
}

// Round 7
// 385.776 us; speedup vs baseline: 1.4909x; 1.1300x over previous
//
#include <hip/hip_runtime.h>
#include <hip/hip_bf16.h>
#include <hip/hip_fp16.h>
#include <math.h>

// MoNet / GMMConv 2-layer GNN on MI355X (gfx950).
// R7: R6 skeleton + LDS-staged double-buffered GEMMs (small LDS, sequential
// 4KB-burst staging, B reused per block) + depth-4 gather pipeline in z1/z2.

#define NF 128
#define NH 64
#define NC 16
#define Z1NODES 16
#define Z1CAP 448
#define Z2NODES 32
#define Z2CAP 576

typedef __bf16 v8bf __attribute__((ext_vector_type(8)));
typedef float v4f __attribute__((ext_vector_type(4)));

__device__ inline ushort f2bu(float x) {
  __hip_bfloat16 h = __float2bfloat16(x);
  return *(ushort*)&h;
}
__device__ inline uint packh2(float a, float b) {
  __half ha = __float2half_rn(a), hb = __float2half_rn(b);
  return (uint)(*(ushort*)&ha) | ((uint)(*(ushort*)&hb) << 16);
}
__device__ inline float2 unph2(uint u) {
  ushort a = (ushort)(u & 0xffff), b = (ushort)(u >> 16);
  return make_float2(__half2float(*(__half*)&a), __half2float(*(__half*)&b));
}
__device__ inline v8bf ld_frag(const ushort* p) {
  uint4 u = *(const uint4*)p;
  return __builtin_bit_cast(v8bf, u);
}

// ---------------- CSR build (verified) ----------------
__global__ __launch_bounds__(256) void hist_kernel(const int* __restrict__ col,
                                                   int* __restrict__ counts, int E) {
  int e = blockIdx.x * 256 + threadIdx.x;
  if (e < E) atomicAdd(&counts[col[e]], 1);
}

__global__ __launch_bounds__(256) void scan1_kernel(const int* __restrict__ counts,
                                                    int* __restrict__ starts,
                                                    int* __restrict__ bsums) {
  __shared__ int wsum[4];
  const int t = threadIdx.x, lane = t & 63, wv = t >> 6;
  int4 v = ((const int4*)counts)[blockIdx.x * 256 + t];
  int tsum = v.x + v.y + v.z + v.w;
  int inc = tsum;
  #pragma unroll
  for (int off = 1; off < 64; off <<= 1) {
    int u = __shfl_up(inc, off, 64);
    if (lane >= off) inc += u;
  }
  if (lane == 63) wsum[wv] = inc;
  __syncthreads();
  int wpre = 0;
  for (int j = 0; j < wv; ++j) wpre += wsum[j];
  int excl = wpre + inc - tsum;
  int4 o;
  o.x = excl; o.y = o.x + v.x; o.z = o.y + v.y; o.w = o.z + v.z;
  ((int4*)starts)[blockIdx.x * 256 + t] = o;
  if (t == 255) bsums[blockIdx.x] = excl + tsum;
}

__global__ __launch_bounds__(64) void scan2_kernel(const int* __restrict__ bsums,
                                                   int* __restrict__ bofs, int NB) {
  int lane = threadIdx.x;
  int v = (lane < NB) ? bsums[lane] : 0;
  int inc = v;
  #pragma unroll
  for (int off = 1; off < 64; off <<= 1) {
    int u = __shfl_up(inc, off, 64);
    if (lane >= off) inc += u;
  }
  if (lane < NB) bofs[lane] = inc - v;
}

__global__ __launch_bounds__(256) void scan3_kernel(int* __restrict__ starts,
                                                    int* __restrict__ cursor,
                                                    const int* __restrict__ bofs) {
  int add = bofs[blockIdx.x];
  int idx = blockIdx.x * 256 + threadIdx.x;
  int4 s = ((int4*)starts)[idx];
  s.x += add; s.y += add; s.z += add; s.w += add;
  ((int4*)starts)[idx] = s;
  ((int4*)cursor)[idx] = s;
}

__global__ __launch_bounds__(256) void fill_kernel(
    const int* __restrict__ row, const int* __restrict__ col,
    const float* __restrict__ eattr,
    const float* __restrict__ mu1, const float* __restrict__ sg1,
    const float* __restrict__ mu2, const float* __restrict__ sg2,
    int* __restrict__ cursor, int* __restrict__ erow,
    uint4* __restrict__ ew1, uint4* __restrict__ ew2, int E) {
  int e = blockIdx.x * 256 + threadIdx.x;
  if (e >= E) return;
  int c = col[e];
  int pos = atomicAdd(&cursor[c], 1);
  float p0 = eattr[2 * e], p1 = eattr[2 * e + 1];
  float w1[8], w2[8];
  #pragma unroll
  for (int k = 0; k < 8; ++k) {
    float d0 = p0 - mu1[2 * k], d1 = p1 - mu1[2 * k + 1];
    float s0 = sg1[2 * k], s1 = sg1[2 * k + 1];
    w1[k] = __expf(-0.5f * (d0 * d0 / (1e-15f + s0 * s0) +
                            d1 * d1 / (1e-15f + s1 * s1)));
    float e0 = p0 - mu2[2 * k], e1 = p1 - mu2[2 * k + 1];
    float t0 = sg2[2 * k], t1 = sg2[2 * k + 1];
    w2[k] = __expf(-0.5f * (e0 * e0 / (1e-15f + t0 * t0) +
                            e1 * e1 / (1e-15f + t1 * t1)));
  }
  erow[pos] = row[e];
  ew1[pos] = make_uint4(packh2(w1[0], w1[1]), packh2(w1[2], w1[3]),
                        packh2(w1[4], w1[5]), packh2(w1[6], w1[7]));
  ew2[pos] = make_uint4(packh2(w2[0], w2[1]), packh2(w2[2], w2[3]),
                        packh2(w2[4], w2[5]), packh2(w2[6], w2[7]));
}

__global__ __launch_bounds__(256) void cast_x_kernel(const float* __restrict__ x,
                                                     ushort* __restrict__ A1, int N) {
  int idx = blockIdx.x * 256 + threadIdx.x;
  if (idx >= N * 32) return;
  int n = idx >> 5, c4 = idx & 31;
  float4 v = ((const float4*)x)[idx];
  ushort4 o;
  o.x = f2bu(v.x); o.y = f2bu(v.y); o.z = f2bu(v.z); o.w = f2bu(v.w);
  *(ushort4*)(A1 + (size_t)n * 1152 + 1024 + c4 * 4) = o;
}

__global__ __launch_bounds__(256) void prep_kernel(
    const float* __restrict__ g1w, const float* __restrict__ r1w,
    const float* __restrict__ g2w, const float* __restrict__ r2w,
    ushort* __restrict__ W1t, ushort* __restrict__ W2t) {
  int i = blockIdx.x * 256 + threadIdx.x;
  if (i < 64 * 1152) {
    int h = i / 1152, j = i % 1152;
    float v = (j < 1024) ? g1w[(size_t)(j & 127) * 512 + (j >> 7) * 64 + h]
                         : r1w[(size_t)(j - 1024) * 64 + h];
    W1t[i] = f2bu(v);
  } else {
    int i2 = i - 64 * 1152;
    if (i2 < 16 * 576) {
      int c = i2 / 576, j = i2 % 576;
      float v = (j < 512) ? g2w[(size_t)(j & 63) * 128 + (j >> 6) * 16 + c]
                          : r2w[(size_t)(j - 512) * 16 + c];
      W2t[i2] = f2bu(v);
    }
  }
}

// ======= z1: Z[n, k*128+f] = (1/deg) sum_e w_ek * x_bf[r_e, f] =======
__global__ __launch_bounds__(256) void z1_kernel(
    ushort* __restrict__ A1, const int* __restrict__ erow,
    const uint4* __restrict__ ew1, const int* __restrict__ starts, int N) {
  __shared__ __align__(16) float lw[Z1CAP][8];
  __shared__ int lrow[Z1CAP];
  const int t = threadIdx.x, lane = t & 63, wv = t >> 6;
  const int base = (int)blockIdx.x * Z1NODES;
  const int S = starts[base];
  const int cl = min(starts[base + Z1NODES] - S, Z1CAP);
  for (int i = t; i < cl; i += 256) {
    lrow[i] = erow[S + i];
    uint4 q = ew1[S + i];
    float2 a = unph2(q.x), b = unph2(q.y), c = unph2(q.z), d = unph2(q.w);
    *(float4*)&lw[i][0] = make_float4(a.x, a.y, b.x, b.y);
    *(float4*)&lw[i][4] = make_float4(c.x, c.y, d.x, d.y);
  }
  __syncthreads();

  for (int i = 0; i < Z1NODES / 4; ++i) {
    const int n = base + wv * 4 + i;
    const int be = starts[n], ee = starts[n + 1];
    float a0[8], a1[8];
    #pragma unroll
    for (int k = 0; k < 8; ++k) { a0[k] = 0.f; a1[k] = 0.f; }
    if (be < ee) {
      const int le = ee - 1;
      auto ROW = [&](int j) -> int {
        int rel = j - S;
        return (rel < cl) ? lrow[rel] : erow[j];
      };
      auto XLD = [&](int j) -> uint {
        return *(const uint*)(A1 + (size_t)ROW(j) * 1152 + 1024 + 2 * lane);
      };
      uint x0 = XLD(be);
      uint x1 = XLD(min(be + 1, le));
      uint x2 = XLD(min(be + 2, le));
      uint x3 = XLD(min(be + 3, le));
      for (int j = be; j <= le; ++j) {
        uint xn = XLD(min(j + 4, le));
        float w8[8];
        int rel = j - S;
        if (rel < cl) {
          float4 lo = *(const float4*)&lw[rel][0];
          float4 hi = *(const float4*)&lw[rel][4];
          w8[0] = lo.x; w8[1] = lo.y; w8[2] = lo.z; w8[3] = lo.w;
          w8[4] = hi.x; w8[5] = hi.y; w8[6] = hi.z; w8[7] = hi.w;
        } else {
          uint4 q = ew1[j];
          float2 a = unph2(q.x), b = unph2(q.y), c = unph2(q.z), d = unph2(q.w);
          w8[0] = a.x; w8[1] = a.y; w8[2] = b.x; w8[3] = b.y;
          w8[4] = c.x; w8[5] = c.y; w8[6] = d.x; w8[7] = d.y;
        }
        float f0 = __uint_as_float(x0 << 16);
        float f1 = __uint_as_float(x0 & 0xffff0000u);
        #pragma unroll
        for (int k = 0; k < 8; ++k) {
          a0[k] = fmaf(w8[k], f0, a0[k]);
          a1[k] = fmaf(w8[k], f1, a1[k]);
        }
        x0 = x1; x1 = x2; x2 = x3; x3 = xn;
      }
    }
    const float inv = 1.f / fmaxf((float)(ee - be), 1.f);
    ushort* zr = A1 + (size_t)n * 1152;
    #pragma unroll
    for (int k = 0; k < 8; ++k) {
      uint pk = (uint)f2bu(a0[k] * inv) | ((uint)f2bu(a1[k] * inv) << 16);
      *(uint*)(zr + k * 128 + 2 * lane) = pk;
    }
  }
}

// ---- gemm1: h_bf = ELU( A1[N2,1152] @ W1t^T + b1 ), LDS-dbuf MFMA ----
// Block: 64 rows, BK=32. A,B tiles staged as contiguous 4KB bursts.
__global__ __launch_bounds__(256) void gemm1_mfma(
    const ushort* __restrict__ A1, const ushort* __restrict__ W1t,
    const float* __restrict__ b1, ushort* __restrict__ h_bf, int N) {
  __shared__ __align__(16) ushort As[2][64 * 32];
  __shared__ __align__(16) ushort Bs[2][64 * 32];
  const int t = threadIdx.x, lane = t & 63, wv = t >> 6;
  const int mfrag = lane & 15, quad = lane >> 4;
  const int m0 = (int)blockIdx.x * 64;
  const int st_r = t >> 2, st_c = (t & 3) * 8;
  const int st_o = st_r * 32 + st_c;
  const ushort* ag = A1 + (size_t)(m0 + st_r) * 1152 + st_c;
  const ushort* bg = W1t + (size_t)st_r * 1152 + st_c;

  {
    uint4 a0 = *(const uint4*)ag;
    uint4 b0 = *(const uint4*)bg;
    *(uint4*)(&As[0][st_o]) = a0;
    *(uint4*)(&Bs[0][st_o]) = b0;
  }
  __syncthreads();

  v4f acc[4];
  #pragma unroll
  for (int ct = 0; ct < 4; ++ct) acc[ct] = (v4f){0.f, 0.f, 0.f, 0.f};

  for (int kc = 0; kc < 36; ++kc) {
    const int cb = kc & 1, nb = cb ^ 1;
    uint4 an, bn;
    if (kc < 35) {
      an = *(const uint4*)(ag + (kc + 1) * 32);
      bn = *(const uint4*)(bg + (kc + 1) * 32);
    }
    v8bf a = ld_frag(&As[cb][(wv * 16 + mfrag) * 32 + quad * 8]);
    #pragma unroll
    for (int ct = 0; ct < 4; ++ct) {
      v8bf b = ld_frag(&Bs[cb][(ct * 16 + mfrag) * 32 + quad * 8]);
      acc[ct] = __builtin_amdgcn_mfma_f32_16x16x32_bf16(a, b, acc[ct], 0, 0, 0);
    }
    if (kc < 35) {
      *(uint4*)(&As[nb][st_o]) = an;
      *(uint4*)(&Bs[nb][st_o]) = bn;
      __syncthreads();
    }
  }
  #pragma unroll
  for (int ct = 0; ct < 4; ++ct) {
    const int colh = ct * 16 + mfrag;
    const float bc = b1[colh];
    #pragma unroll
    for (int r = 0; r < 4; ++r) {
      int node = m0 + wv * 16 + quad * 4 + r;
      if (node < N) {
        float v = acc[ct][r] + bc;
        v = v > 0.f ? v : expm1f(v);
        h_bf[(size_t)node * NH + colh] = f2bu(v);
      }
    }
  }
}

// ======= z2: Z2[n, k*64+f] = (1/deg) sum_e w_ek * h_bf[r_e, f] =======
__global__ __launch_bounds__(256) void z2_kernel(
    const ushort* __restrict__ h_bf, ushort* __restrict__ Z2,
    const int* __restrict__ erow, const uint4* __restrict__ ew2,
    const int* __restrict__ starts, int N) {
  __shared__ __align__(16) float lw[Z2CAP][8];
  __shared__ int lrow[Z2CAP];
  const int t = threadIdx.x, lane = t & 63, wv = t >> 6;
  const int base = (int)blockIdx.x * Z2NODES;
  const int S = starts[base];
  const int cl = min(starts[base + Z2NODES] - S, Z2CAP);
  for (int i = t; i < cl; i += 256) {
    lrow[i] = erow[S + i];
    uint4 q = ew2[S + i];
    float2 a = unph2(q.x), b = unph2(q.y), c = unph2(q.z), d = unph2(q.w);
    *(float4*)&lw[i][0] = make_float4(a.x, a.y, b.x, b.y);
    *(float4*)&lw[i][4] = make_float4(c.x, c.y, d.x, d.y);
  }
  __syncthreads();

  for (int i = 0; i < Z2NODES / 4; ++i) {
    const int n = base + wv * 8 + i;
    if (n >= N) continue;
    const int be = starts[n], ee = starts[n + 1];
    float acc[8];
    #pragma unroll
    for (int k = 0; k < 8; ++k) acc[k] = 0.f;
    if (be < ee) {
      const int le = ee - 1;
      auto ROW = [&](int j) -> int {
        int rel = j - S;
        return (rel < cl) ? lrow[rel] : erow[j];
      };
      auto HLD = [&](int j) -> ushort {
        return h_bf[(size_t)ROW(j) * NH + lane];
      };
      ushort x0 = HLD(be);
      ushort x1 = HLD(min(be + 1, le));
      ushort x2 = HLD(min(be + 2, le));
      ushort x3 = HLD(min(be + 3, le));
      for (int j = be; j <= le; ++j) {
        ushort xn = HLD(min(j + 4, le));
        float w8[8];
        int rel = j - S;
        if (rel < cl) {
          float4 lo = *(const float4*)&lw[rel][0];
          float4 hi = *(const float4*)&lw[rel][4];
          w8[0] = lo.x; w8[1] = lo.y; w8[2] = lo.z; w8[3] = lo.w;
          w8[4] = hi.x; w8[5] = hi.y; w8[6] = hi.z; w8[7] = hi.w;
        } else {
          uint4 q = ew2[j];
          float2 a = unph2(q.x), b = unph2(q.y), c = unph2(q.z), d = unph2(q.w);
          w8[0] = a.x; w8[1] = a.y; w8[2] = b.x; w8[3] = b.y;
          w8[4] = c.x; w8[5] = c.y; w8[6] = d.x; w8[7] = d.y;
        }
        float f = __uint_as_float(((uint)x0) << 16);
        #pragma unroll
        for (int k = 0; k < 8; ++k) acc[k] = fmaf(w8[k], f, acc[k]);
        x0 = x1; x1 = x2; x2 = x3; x3 = xn;
      }
    }
    const float inv = 1.f / fmaxf((float)(ee - be), 1.f);
    ushort* zr = Z2 + (size_t)n * 512;
    #pragma unroll
    for (int k = 0; k < 8; ++k) zr[k * 64 + lane] = f2bu(acc[k] * inv);
  }
}

// ---- gemm2: out = log_softmax( [Z2 | h_bf] @ W2t^T + b2 ), LDS-dbuf ----
#define W2ST 584   // padded stride (shorts): kills 16-way broadcast conflicts
__global__ __launch_bounds__(256) void gemm2_mfma(
    const ushort* __restrict__ Z2, const ushort* __restrict__ h_bf,
    const ushort* __restrict__ W2t, const float* __restrict__ b2,
    float* __restrict__ out, int N) {
  __shared__ __align__(16) ushort As[2][64 * 32];
  __shared__ __align__(16) ushort Ws[16 * W2ST];
  const int t = threadIdx.x, lane = t & 63, wv = t >> 6;
  const int mfrag = lane & 15, quad = lane >> 4;
  const int m0 = (int)blockIdx.x * 64;
  // stage all of W2 (16x576) once
  for (int i = t; i < 1152; i += 256) {
    int r = i / 72, c = (i % 72) * 8;
    *(uint4*)(&Ws[r * W2ST + c]) = *(const uint4*)(W2t + (size_t)r * 576 + c);
  }
  const int st_r = t >> 2, st_c = (t & 3) * 8;
  const int st_o = st_r * 32 + st_c;
  const ushort* zg = Z2 + (size_t)(m0 + st_r) * 512 + st_c;
  const ushort* hg = h_bf + (size_t)(m0 + st_r) * 64 + st_c;

  {
    uint4 a0 = *(const uint4*)zg;
    *(uint4*)(&As[0][st_o]) = a0;
  }
  __syncthreads();

  v4f acc = (v4f){0.f, 0.f, 0.f, 0.f};
  for (int kc = 0; kc < 18; ++kc) {
    const int cb = kc & 1, nb = cb ^ 1;
    uint4 an;
    if (kc < 17) {
      int k1 = kc + 1;
      an = (k1 < 16) ? *(const uint4*)(zg + k1 * 32)
                     : *(const uint4*)(hg + (k1 - 16) * 32);
    }
    v8bf a = ld_frag(&As[cb][(wv * 16 + mfrag) * 32 + quad * 8]);
    v8bf b = ld_frag(&Ws[mfrag * W2ST + kc * 32 + quad * 8]);
    acc = __builtin_amdgcn_mfma_f32_16x16x32_bf16(a, b, acc, 0, 0, 0);
    if (kc < 17) {
      *(uint4*)(&As[nb][st_o]) = an;
      __syncthreads();
    }
  }
  const float bc = b2[mfrag];
  #pragma unroll
  for (int r = 0; r < 4; ++r) {
    int node = m0 + wv * 16 + quad * 4 + r;
    float v = acc[r] + bc;
    float mx = v;
    #pragma unroll
    for (int off = 8; off >= 1; off >>= 1) mx = fmaxf(mx, __shfl_xor(mx, off, 64));
    float sm = __expf(v - mx);
    #pragma unroll
    for (int off = 8; off >= 1; off >>= 1) sm += __shfl_xor(sm, off, 64);
    if (node < N) out[(size_t)node * NC + mfrag] = v - mx - __logf(sm);
  }
}

extern "C" void kernel_launch(void* const* d_in, const int* in_sizes, int n_in,
                              void* d_out, int out_size, void* d_ws, size_t ws_size,
                              hipStream_t stream) {
  const float* x     = (const float*)d_in[0];
  const int*   eidx  = (const int*)d_in[1];
  const float* eattr = (const float*)d_in[2];
  const float* g1w   = (const float*)d_in[3];
  const float* mu1   = (const float*)d_in[4];
  const float* sg1   = (const float*)d_in[5];
  const float* r1w   = (const float*)d_in[6];
  const float* b1    = (const float*)d_in[7];
  const float* g2w   = (const float*)d_in[8];
  const float* mu2   = (const float*)d_in[9];
  const float* sg2   = (const float*)d_in[10];
  const float* r2w   = (const float*)d_in[11];
  const float* b2    = (const float*)d_in[12];

  const int N = in_sizes[0] / NF;        // 50000
  const int E = in_sizes[1] / 2;         // 800000
  const int* row = eidx;
  const int* col = eidx + E;
  const int N2 = (N + 63) & ~63;         // 50048
  const int NP = (N + 1023) & ~1023;     // 50176
  const int NB = NP / 1024;              // 49

  uint4* ew1   = (uint4*)d_ws;                         // E
  uint4* ew2   = ew1 + (size_t)E;                      // E
  ushort* A1   = (ushort*)(ew2 + (size_t)E);           // N2*1152; Z2 aliases
  ushort* Z2   = A1;                                   // [N2,512] after gemm1
  ushort* h_bf = A1 + (size_t)N2 * 1152;               // N2*64
  ushort* W1t  = h_bf + (size_t)N2 * NH;               // 64*1152
  ushort* W2t  = W1t + (size_t)64 * 1152;              // 16*576
  int* erow    = (int*)(W2t + (size_t)16 * 576);       // E
  int* counts  = erow + (size_t)E;                     // NP
  int* starts  = counts + NP;                          // NP
  int* cursor  = starts + NP;                          // NP
  int* bsums   = cursor + NP;                          // 64
  int* bofs    = bsums + 64;                           // 64

  hipMemsetAsync(counts, 0, (size_t)NP * sizeof(int), stream);
  hist_kernel<<<(E + 255) / 256, 256, 0, stream>>>(col, counts, E);
  scan1_kernel<<<NB, 256, 0, stream>>>(counts, starts, bsums);
  scan2_kernel<<<1, 64, 0, stream>>>(bsums, bofs, NB);
  scan3_kernel<<<NB, 256, 0, stream>>>(starts, cursor, bofs);
  fill_kernel<<<(E + 255) / 256, 256, 0, stream>>>(row, col, eattr, mu1, sg1,
                                                   mu2, sg2, cursor, erow,
                                                   ew1, ew2, E);
  cast_x_kernel<<<(N * 32 + 255) / 256, 256, 0, stream>>>(x, A1, N);
  prep_kernel<<<(64 * 1152 + 16 * 576 + 255) / 256, 256, 0, stream>>>(
      g1w, r1w, g2w, r2w, W1t, W2t);

  z1_kernel<<<N / Z1NODES, 256, 0, stream>>>(A1, erow, ew1, starts, N);
  gemm1_mfma<<<N2 / 64, 256, 0, stream>>>(A1, W1t, b1, h_bf, N);
  z2_kernel<<<(N + Z2NODES - 1) / Z2NODES, 256, 0, stream>>>(h_bf, Z2, erow,
                                                             ew2, starts, N);
  gemm2_mfma<<<N2 / 64, 256, 0, stream>>>(Z2, h_bf, W2t, b2, (float*)d_out, N);
}

// Round 8
// 384.589 us; speedup vs baseline: 1.4955x; 1.0031x over previous
//
#include <hip/hip_runtime.h>
#include <hip/hip_bf16.h>
#include <hip/hip_fp16.h>
#include <math.h>

// MoNet / GMMConv 2-layer GNN on MI355X (gfx950).
// R8: layer 2 goes direct-form: gx2e = h @ [perm(g2w)|r2w] (bf16, [N,160]
// padded, L2-resident), then ONE edge kernel aggregates + root + bias +
// log_softmax straight into d_out. Z2 write/read and gemm2 eliminated.
// Layer 1 (z1 + gemm1) and CSR build unchanged from R7.

#define NF 128
#define NH 64
#define NC 16
#define Z1NODES 16
#define Z1CAP 448
#define E2NODES 16
#define E2CAP 288
#define GXST 160   // gx2e row stride in ushorts (144 cols + pad, 320B rows)

typedef __bf16 v8bf __attribute__((ext_vector_type(8)));
typedef float v4f __attribute__((ext_vector_type(4)));

__device__ inline ushort f2bu(float x) {
  __hip_bfloat16 h = __float2bfloat16(x);
  return *(ushort*)&h;
}
__device__ inline uint packh2(float a, float b) {
  __half ha = __float2half_rn(a), hb = __float2half_rn(b);
  return (uint)(*(ushort*)&ha) | ((uint)(*(ushort*)&hb) << 16);
}
__device__ inline float2 unph2(uint u) {
  ushort a = (ushort)(u & 0xffff), b = (ushort)(u >> 16);
  return make_float2(__half2float(*(__half*)&a), __half2float(*(__half*)&b));
}
__device__ inline v8bf ld_frag(const ushort* p) {
  uint4 u = *(const uint4*)p;
  return __builtin_bit_cast(v8bf, u);
}

// ---------------- CSR build (verified) ----------------
__global__ __launch_bounds__(256) void hist_kernel(const int* __restrict__ col,
                                                   int* __restrict__ counts, int E) {
  int e = blockIdx.x * 256 + threadIdx.x;
  if (e < E) atomicAdd(&counts[col[e]], 1);
}

__global__ __launch_bounds__(256) void scan1_kernel(const int* __restrict__ counts,
                                                    int* __restrict__ starts,
                                                    int* __restrict__ bsums) {
  __shared__ int wsum[4];
  const int t = threadIdx.x, lane = t & 63, wv = t >> 6;
  int4 v = ((const int4*)counts)[blockIdx.x * 256 + t];
  int tsum = v.x + v.y + v.z + v.w;
  int inc = tsum;
  #pragma unroll
  for (int off = 1; off < 64; off <<= 1) {
    int u = __shfl_up(inc, off, 64);
    if (lane >= off) inc += u;
  }
  if (lane == 63) wsum[wv] = inc;
  __syncthreads();
  int wpre = 0;
  for (int j = 0; j < wv; ++j) wpre += wsum[j];
  int excl = wpre + inc - tsum;
  int4 o;
  o.x = excl; o.y = o.x + v.x; o.z = o.y + v.y; o.w = o.z + v.z;
  ((int4*)starts)[blockIdx.x * 256 + t] = o;
  if (t == 255) bsums[blockIdx.x] = excl + tsum;
}

__global__ __launch_bounds__(64) void scan2_kernel(const int* __restrict__ bsums,
                                                   int* __restrict__ bofs, int NB) {
  int lane = threadIdx.x;
  int v = (lane < NB) ? bsums[lane] : 0;
  int inc = v;
  #pragma unroll
  for (int off = 1; off < 64; off <<= 1) {
    int u = __shfl_up(inc, off, 64);
    if (lane >= off) inc += u;
  }
  if (lane < NB) bofs[lane] = inc - v;
}

__global__ __launch_bounds__(256) void scan3_kernel(int* __restrict__ starts,
                                                    int* __restrict__ cursor,
                                                    const int* __restrict__ bofs) {
  int add = bofs[blockIdx.x];
  int idx = blockIdx.x * 256 + threadIdx.x;
  int4 s = ((int4*)starts)[idx];
  s.x += add; s.y += add; s.z += add; s.w += add;
  ((int4*)starts)[idx] = s;
  ((int4*)cursor)[idx] = s;
}

__global__ __launch_bounds__(256) void fill_kernel(
    const int* __restrict__ row, const int* __restrict__ col,
    const float* __restrict__ eattr,
    const float* __restrict__ mu1, const float* __restrict__ sg1,
    const float* __restrict__ mu2, const float* __restrict__ sg2,
    int* __restrict__ cursor, int* __restrict__ erow,
    uint4* __restrict__ ew1, uint4* __restrict__ ew2, int E) {
  int e = blockIdx.x * 256 + threadIdx.x;
  if (e >= E) return;
  int c = col[e];
  int pos = atomicAdd(&cursor[c], 1);
  float p0 = eattr[2 * e], p1 = eattr[2 * e + 1];
  float w1[8], w2[8];
  #pragma unroll
  for (int k = 0; k < 8; ++k) {
    float d0 = p0 - mu1[2 * k], d1 = p1 - mu1[2 * k + 1];
    float s0 = sg1[2 * k], s1 = sg1[2 * k + 1];
    w1[k] = __expf(-0.5f * (d0 * d0 / (1e-15f + s0 * s0) +
                            d1 * d1 / (1e-15f + s1 * s1)));
    float e0 = p0 - mu2[2 * k], e1 = p1 - mu2[2 * k + 1];
    float t0 = sg2[2 * k], t1 = sg2[2 * k + 1];
    w2[k] = __expf(-0.5f * (e0 * e0 / (1e-15f + t0 * t0) +
                            e1 * e1 / (1e-15f + t1 * t1)));
  }
  erow[pos] = row[e];
  ew1[pos] = make_uint4(packh2(w1[0], w1[1]), packh2(w1[2], w1[3]),
                        packh2(w1[4], w1[5]), packh2(w1[6], w1[7]));
  ew2[pos] = make_uint4(packh2(w2[0], w2[1]), packh2(w2[2], w2[3]),
                        packh2(w2[4], w2[5]), packh2(w2[6], w2[7]));
}

__global__ __launch_bounds__(256) void cast_x_kernel(const float* __restrict__ x,
                                                     ushort* __restrict__ A1, int N) {
  int idx = blockIdx.x * 256 + threadIdx.x;
  if (idx >= N * 32) return;
  int n = idx >> 5, c4 = idx & 31;
  float4 v = ((const float4*)x)[idx];
  ushort4 o;
  o.x = f2bu(v.x); o.y = f2bu(v.y); o.z = f2bu(v.z); o.w = f2bu(v.w);
  *(ushort4*)(A1 + (size_t)n * 1152 + 1024 + c4 * 4) = o;
}

// ---- prep: W1t as before; G2pT[c'][f] (144x64) permuted [g2w|r2w] ----
// c' < 128: kq=c'>>5, rem=c'&31, o=rem>>1, k=2*kq+(rem&1) -> g2w[f][k*16+o]
// c' >= 128: r2w[f][c'-128]
__global__ __launch_bounds__(256) void prep_kernel(
    const float* __restrict__ g1w, const float* __restrict__ r1w,
    const float* __restrict__ g2w, const float* __restrict__ r2w,
    ushort* __restrict__ W1t, ushort* __restrict__ G2pT) {
  int i = blockIdx.x * 256 + threadIdx.x;
  if (i < 64 * 1152) {
    int h = i / 1152, j = i % 1152;
    float v = (j < 1024) ? g1w[(size_t)(j & 127) * 512 + (j >> 7) * 64 + h]
                         : r1w[(size_t)(j - 1024) * 64 + h];
    W1t[i] = f2bu(v);
  } else {
    int i2 = i - 64 * 1152;
    if (i2 < 144 * 64) {
      int cp = i2 / 64, f = i2 % 64;
      float v;
      if (cp < 128) {
        int kq = cp >> 5, rem = cp & 31;
        int o = rem >> 1, k = kq * 2 + (rem & 1);
        v = g2w[(size_t)f * 128 + k * 16 + o];
      } else {
        v = r2w[(size_t)f * 16 + (cp - 128)];
      }
      G2pT[i2] = f2bu(v);
    }
  }
}

// ======= z1 (unchanged R7): Z[n,k*128+f] = (1/deg) sum w_ek x_bf[r,f] =======
__global__ __launch_bounds__(256) void z1_kernel(
    ushort* __restrict__ A1, const int* __restrict__ erow,
    const uint4* __restrict__ ew1, const int* __restrict__ starts, int N) {
  __shared__ __align__(16) float lw[Z1CAP][8];
  __shared__ int lrow[Z1CAP];
  const int t = threadIdx.x, lane = t & 63, wv = t >> 6;
  const int base = (int)blockIdx.x * Z1NODES;
  const int S = starts[base];
  const int cl = min(starts[base + Z1NODES] - S, Z1CAP);
  for (int i = t; i < cl; i += 256) {
    lrow[i] = erow[S + i];
    uint4 q = ew1[S + i];
    float2 a = unph2(q.x), b = unph2(q.y), c = unph2(q.z), d = unph2(q.w);
    *(float4*)&lw[i][0] = make_float4(a.x, a.y, b.x, b.y);
    *(float4*)&lw[i][4] = make_float4(c.x, c.y, d.x, d.y);
  }
  __syncthreads();

  for (int i = 0; i < Z1NODES / 4; ++i) {
    const int n = base + wv * 4 + i;
    const int be = starts[n], ee = starts[n + 1];
    float a0[8], a1[8];
    #pragma unroll
    for (int k = 0; k < 8; ++k) { a0[k] = 0.f; a1[k] = 0.f; }
    if (be < ee) {
      const int le = ee - 1;
      auto ROW = [&](int j) -> int {
        int rel = j - S;
        return (rel < cl) ? lrow[rel] : erow[j];
      };
      auto XLD = [&](int j) -> uint {
        return *(const uint*)(A1 + (size_t)ROW(j) * 1152 + 1024 + 2 * lane);
      };
      uint x0 = XLD(be);
      uint x1 = XLD(min(be + 1, le));
      uint x2 = XLD(min(be + 2, le));
      uint x3 = XLD(min(be + 3, le));
      for (int j = be; j <= le; ++j) {
        uint xn = XLD(min(j + 4, le));
        float w8[8];
        int rel = j - S;
        if (rel < cl) {
          float4 lo = *(const float4*)&lw[rel][0];
          float4 hi = *(const float4*)&lw[rel][4];
          w8[0] = lo.x; w8[1] = lo.y; w8[2] = lo.z; w8[3] = lo.w;
          w8[4] = hi.x; w8[5] = hi.y; w8[6] = hi.z; w8[7] = hi.w;
        } else {
          uint4 q = ew1[j];
          float2 a = unph2(q.x), b = unph2(q.y), c = unph2(q.z), d = unph2(q.w);
          w8[0] = a.x; w8[1] = a.y; w8[2] = b.x; w8[3] = b.y;
          w8[4] = c.x; w8[5] = c.y; w8[6] = d.x; w8[7] = d.y;
        }
        float f0 = __uint_as_float(x0 << 16);
        float f1 = __uint_as_float(x0 & 0xffff0000u);
        #pragma unroll
        for (int k = 0; k < 8; ++k) {
          a0[k] = fmaf(w8[k], f0, a0[k]);
          a1[k] = fmaf(w8[k], f1, a1[k]);
        }
        x0 = x1; x1 = x2; x2 = x3; x3 = xn;
      }
    }
    const float inv = 1.f / fmaxf((float)(ee - be), 1.f);
    ushort* zr = A1 + (size_t)n * 1152;
    #pragma unroll
    for (int k = 0; k < 8; ++k) {
      uint pk = (uint)f2bu(a0[k] * inv) | ((uint)f2bu(a1[k] * inv) << 16);
      *(uint*)(zr + k * 128 + 2 * lane) = pk;
    }
  }
}

// ---- gemm1 (unchanged R7): h_bf = ELU( A1 @ W1t^T + b1 ), LDS-dbuf ----
__global__ __launch_bounds__(256) void gemm1_mfma(
    const ushort* __restrict__ A1, const ushort* __restrict__ W1t,
    const float* __restrict__ b1, ushort* __restrict__ h_bf, int N) {
  __shared__ __align__(16) ushort As[2][64 * 32];
  __shared__ __align__(16) ushort Bs[2][64 * 32];
  const int t = threadIdx.x, lane = t & 63, wv = t >> 6;
  const int mfrag = lane & 15, quad = lane >> 4;
  const int m0 = (int)blockIdx.x * 64;
  const int st_r = t >> 2, st_c = (t & 3) * 8;
  const int st_o = st_r * 32 + st_c;
  const ushort* ag = A1 + (size_t)(m0 + st_r) * 1152 + st_c;
  const ushort* bg = W1t + (size_t)st_r * 1152 + st_c;

  {
    uint4 a0 = *(const uint4*)ag;
    uint4 b0 = *(const uint4*)bg;
    *(uint4*)(&As[0][st_o]) = a0;
    *(uint4*)(&Bs[0][st_o]) = b0;
  }
  __syncthreads();

  v4f acc[4];
  #pragma unroll
  for (int ct = 0; ct < 4; ++ct) acc[ct] = (v4f){0.f, 0.f, 0.f, 0.f};

  for (int kc = 0; kc < 36; ++kc) {
    const int cb = kc & 1, nb = cb ^ 1;
    uint4 an, bn;
    if (kc < 35) {
      an = *(const uint4*)(ag + (kc + 1) * 32);
      bn = *(const uint4*)(bg + (kc + 1) * 32);
    }
    v8bf a = ld_frag(&As[cb][(wv * 16 + mfrag) * 32 + quad * 8]);
    #pragma unroll
    for (int ct = 0; ct < 4; ++ct) {
      v8bf b = ld_frag(&Bs[cb][(ct * 16 + mfrag) * 32 + quad * 8]);
      acc[ct] = __builtin_amdgcn_mfma_f32_16x16x32_bf16(a, b, acc[ct], 0, 0, 0);
    }
    if (kc < 35) {
      *(uint4*)(&As[nb][st_o]) = an;
      *(uint4*)(&Bs[nb][st_o]) = bn;
      __syncthreads();
    }
  }
  #pragma unroll
  for (int ct = 0; ct < 4; ++ct) {
    const int colh = ct * 16 + mfrag;
    const float bc = b1[colh];
    #pragma unroll
    for (int r = 0; r < 4; ++r) {
      int node = m0 + wv * 16 + quad * 4 + r;
      if (node < N) {
        float v = acc[ct][r] + bc;
        v = v > 0.f ? v : expm1f(v);
        h_bf[(size_t)node * NH + colh] = f2bu(v);
      }
    }
  }
}

// ---- gemm2a: gx2e[N,160] = bf16( h_bf @ G2pT^T ), LDS-free MFMA ----
__global__ __launch_bounds__(256) void gemm2a_kernel(
    const ushort* __restrict__ h_bf, const ushort* __restrict__ G2pT,
    ushort* __restrict__ gx2e, int N) {
  const int t = threadIdx.x, lane = t & 63, wv = t >> 6;
  const int mfrag = lane & 15, quad = lane >> 4;
  const int m0 = (int)blockIdx.x * 64 + wv * 16;
  v4f acc[9];
  #pragma unroll
  for (int t9 = 0; t9 < 9; ++t9) acc[t9] = (v4f){0.f, 0.f, 0.f, 0.f};
  const ushort* arow = h_bf + (size_t)(m0 + mfrag) * 64 + quad * 8;
  const ushort* brow = G2pT + (size_t)mfrag * 64 + quad * 8;
  #pragma unroll
  for (int kc = 0; kc < 2; ++kc) {
    v8bf a = ld_frag(arow + kc * 32);
    #pragma unroll
    for (int t9 = 0; t9 < 9; ++t9) {
      v8bf b = ld_frag(brow + (size_t)t9 * 16 * 64 + kc * 32);
      acc[t9] = __builtin_amdgcn_mfma_f32_16x16x32_bf16(a, b, acc[t9], 0, 0, 0);
    }
  }
  #pragma unroll
  for (int t9 = 0; t9 < 9; ++t9) {
    #pragma unroll
    for (int r = 0; r < 4; ++r) {
      int node = m0 + quad * 4 + r;
      if (node < N)
        gx2e[(size_t)node * GXST + t9 * 16 + mfrag] = f2bu(acc[t9][r]);
    }
  }
}

// ==== edge2: out = lsm( (sum_e w.gx2e[r])/deg + root + b2 ) -> d_out ====
// 16 nodes/block (4/wave). Per edge per lane: 1 uint load (row coalesced),
// 1 ds_read_b64 weight pair, 2 cvt, 2 FMA. Epilogue fully in-wave.
__global__ __launch_bounds__(256) void edge2_kernel(
    const ushort* __restrict__ gx2e, const int* __restrict__ erow,
    const uint4* __restrict__ ew2, const int* __restrict__ starts,
    const float* __restrict__ b2, float* __restrict__ out, int N) {
  __shared__ __align__(16) float lw[E2CAP][8];
  __shared__ int lrow[E2CAP];
  __shared__ float lb2[16];
  const int t = threadIdx.x, lane = t & 63, wv = t >> 6;
  const int base = (int)blockIdx.x * E2NODES;
  const int S = starts[base];
  const int cl = min(starts[base + E2NODES] - S, E2CAP);
  if (t < 16) lb2[t] = b2[t];
  for (int i = t; i < cl; i += 256) {
    lrow[i] = erow[S + i];
    uint4 q = ew2[S + i];
    float2 a = unph2(q.x), b = unph2(q.y), c = unph2(q.z), d = unph2(q.w);
    *(float4*)&lw[i][0] = make_float4(a.x, a.y, b.x, b.y);
    *(float4*)&lw[i][4] = make_float4(c.x, c.y, d.x, d.y);
  }
  __syncthreads();

  const int o = lane & 15, kq = lane >> 4;
  const int loff = kq * 64 + o * 4;           // byte offset within 320B row
  const char* gbase = (const char*)gx2e;

  for (int i = 0; i < E2NODES / 4; ++i) {
    const int n = base + wv * 4 + i;
    if (n >= N) continue;
    const int be = starts[n], ee = starts[n + 1];
    float acc0 = 0.f, acc1 = 0.f;
    if (be < ee) {
      const int le = ee - 1;
      auto ROW = [&](int j) -> int {
        int rel = j - S;
        return (rel < cl) ? lrow[rel] : erow[j];
      };
      auto GLD = [&](int j) -> uint {
        return *(const uint*)(gbase + (size_t)ROW(j) * 320 + loff);
      };
      uint g0 = GLD(be);
      uint g1 = GLD(min(be + 1, le));
      uint g2 = GLD(min(be + 2, le));
      uint g3 = GLD(min(be + 3, le));
      for (int j = be; j <= le; ++j) {
        uint gn = GLD(min(j + 4, le));
        float wA, wB;
        int rel = j - S;
        if (rel < cl) {
          float2 wp = *(const float2*)&lw[rel][kq * 2];
          wA = wp.x; wB = wp.y;
        } else {
          uint4 q = ew2[j];
          uint comp = (kq == 0) ? q.x : (kq == 1) ? q.y : (kq == 2) ? q.z : q.w;
          float2 wp = unph2(comp);
          wA = wp.x; wB = wp.y;
        }
        float f0 = __uint_as_float(g0 << 16);          // k = 2*kq
        float f1 = __uint_as_float(g0 & 0xffff0000u);  // k = 2*kq+1
        acc0 = fmaf(wA, f0, acc0);
        acc1 = fmaf(wB, f1, acc1);
        g0 = g1; g1 = g2; g2 = g3; g3 = gn;
      }
    }
    float s = acc0 + acc1;
    s += __shfl_xor(s, 16, 64);
    s += __shfl_xor(s, 32, 64);                 // sum over all 8 kernels
    const float inv = 1.f / fmaxf((float)(ee - be), 1.f);
    ushort ru = *(const ushort*)(gbase + (size_t)n * 320 + 256 + o * 2);
    float root = __uint_as_float(((uint)ru) << 16);
    float v = s * inv + root + lb2[o];
    float mx = v;
    #pragma unroll
    for (int off = 8; off >= 1; off >>= 1) mx = fmaxf(mx, __shfl_xor(mx, off, 64));
    float sm = __expf(v - mx);
    #pragma unroll
    for (int off = 8; off >= 1; off >>= 1) sm += __shfl_xor(sm, off, 64);
    if (kq == 0) out[(size_t)n * NC + o] = v - mx - __logf(sm);
  }
}

extern "C" void kernel_launch(void* const* d_in, const int* in_sizes, int n_in,
                              void* d_out, int out_size, void* d_ws, size_t ws_size,
                              hipStream_t stream) {
  const float* x     = (const float*)d_in[0];
  const int*   eidx  = (const int*)d_in[1];
  const float* eattr = (const float*)d_in[2];
  const float* g1w   = (const float*)d_in[3];
  const float* mu1   = (const float*)d_in[4];
  const float* sg1   = (const float*)d_in[5];
  const float* r1w   = (const float*)d_in[6];
  const float* b1    = (const float*)d_in[7];
  const float* g2w   = (const float*)d_in[8];
  const float* mu2   = (const float*)d_in[9];
  const float* sg2   = (const float*)d_in[10];
  const float* r2w   = (const float*)d_in[11];
  const float* b2    = (const float*)d_in[12];

  const int N = in_sizes[0] / NF;        // 50000
  const int E = in_sizes[1] / 2;         // 800000
  const int* row = eidx;
  const int* col = eidx + E;
  const int N2 = (N + 63) & ~63;         // 50048
  const int NP = (N + 1023) & ~1023;     // 50176
  const int NB = NP / 1024;              // 49

  uint4* ew1   = (uint4*)d_ws;                         // E
  uint4* ew2   = ew1 + (size_t)E;                      // E
  ushort* A1   = (ushort*)(ew2 + (size_t)E);           // N2*1152 (Z1|x)
  ushort* gx2e = A1;                                   // [N2,160] after gemm1
  ushort* h_bf = A1 + (size_t)N2 * 1152;               // N2*64
  ushort* W1t  = h_bf + (size_t)N2 * NH;               // 64*1152
  ushort* G2pT = W1t + (size_t)64 * 1152;              // 144*64
  int* erow    = (int*)(G2pT + (size_t)144 * 64);      // E
  int* counts  = erow + (size_t)E;                     // NP
  int* starts  = counts + NP;                          // NP
  int* cursor  = starts + NP;                          // NP
  int* bsums   = cursor + NP;                          // 64
  int* bofs    = bsums + 64;                           // 64

  hipMemsetAsync(counts, 0, (size_t)NP * sizeof(int), stream);
  hist_kernel<<<(E + 255) / 256, 256, 0, stream>>>(col, counts, E);
  scan1_kernel<<<NB, 256, 0, stream>>>(counts, starts, bsums);
  scan2_kernel<<<1, 64, 0, stream>>>(bsums, bofs, NB);
  scan3_kernel<<<NB, 256, 0, stream>>>(starts, cursor, bofs);
  fill_kernel<<<(E + 255) / 256, 256, 0, stream>>>(row, col, eattr, mu1, sg1,
                                                   mu2, sg2, cursor, erow,
                                                   ew1, ew2, E);
  cast_x_kernel<<<(N * 32 + 255) / 256, 256, 0, stream>>>(x, A1, N);
  prep_kernel<<<(64 * 1152 + 144 * 64 + 255) / 256, 256, 0, stream>>>(
      g1w, r1w, g2w, r2w, W1t, G2pT);

  z1_kernel<<<N / Z1NODES, 256, 0, stream>>>(A1, erow, ew1, starts, N);
  gemm1_mfma<<<N2 / 64, 256, 0, stream>>>(A1, W1t, b1, h_bf, N);
  gemm2a_kernel<<<N2 / 64, 256, 0, stream>>>(h_bf, G2pT, gx2e, N);
  edge2_kernel<<<(N + E2NODES - 1) / E2NODES, 256, 0, stream>>>(
      gx2e, erow, ew2, starts, b2, (float*)d_out, N);
}

// Round 9
// 371.507 us; speedup vs baseline: 1.5482x; 1.0352x over previous
//
#include <hip/hip_runtime.h>
#include <hip/hip_bf16.h>
#include <hip/hip_fp16.h>
#include <math.h>

// MoNet / GMMConv 2-layer GNN on MI355X (gfx950).
// R9: R8 skeleton; z1/edge2 inner loops stripped to essentials:
//   - pre-scaled byte offsets in LDS (1 add per edge for addressing)
//   - sentinel-padded meta arrays (no min clamps)
//   - split LDS-window / global-tail loops (no per-edge source select)
//   - depth-2 explicit prefetch of (off, w, g)
// Everything else identical to R8.

#define NF 128
#define NH 64
#define NC 16
#define Z1NODES 16
#define Z1CAP 448
#define E2NODES 16
#define E2CAP 320
#define GXST 160   // gx2e row stride in ushorts (144 cols + pad, 320B rows)

typedef __bf16 v8bf __attribute__((ext_vector_type(8)));
typedef float v4f __attribute__((ext_vector_type(4)));

__device__ inline ushort f2bu(float x) {
  __hip_bfloat16 h = __float2bfloat16(x);
  return *(ushort*)&h;
}
__device__ inline uint packh2(float a, float b) {
  __half ha = __float2half_rn(a), hb = __float2half_rn(b);
  return (uint)(*(ushort*)&ha) | ((uint)(*(ushort*)&hb) << 16);
}
__device__ inline float2 unph2(uint u) {
  ushort a = (ushort)(u & 0xffff), b = (ushort)(u >> 16);
  return make_float2(__half2float(*(__half*)&a), __half2float(*(__half*)&b));
}
__device__ inline v8bf ld_frag(const ushort* p) {
  uint4 u = *(const uint4*)p;
  return __builtin_bit_cast(v8bf, u);
}

// ---------------- CSR build (verified) ----------------
__global__ __launch_bounds__(256) void hist_kernel(const int* __restrict__ col,
                                                   int* __restrict__ counts, int E) {
  int e = blockIdx.x * 256 + threadIdx.x;
  if (e < E) atomicAdd(&counts[col[e]], 1);
}

__global__ __launch_bounds__(256) void scan1_kernel(const int* __restrict__ counts,
                                                    int* __restrict__ starts,
                                                    int* __restrict__ bsums) {
  __shared__ int wsum[4];
  const int t = threadIdx.x, lane = t & 63, wv = t >> 6;
  int4 v = ((const int4*)counts)[blockIdx.x * 256 + t];
  int tsum = v.x + v.y + v.z + v.w;
  int inc = tsum;
  #pragma unroll
  for (int off = 1; off < 64; off <<= 1) {
    int u = __shfl_up(inc, off, 64);
    if (lane >= off) inc += u;
  }
  if (lane == 63) wsum[wv] = inc;
  __syncthreads();
  int wpre = 0;
  for (int j = 0; j < wv; ++j) wpre += wsum[j];
  int excl = wpre + inc - tsum;
  int4 o;
  o.x = excl; o.y = o.x + v.x; o.z = o.y + v.y; o.w = o.z + v.z;
  ((int4*)starts)[blockIdx.x * 256 + t] = o;
  if (t == 255) bsums[blockIdx.x] = excl + tsum;
}

__global__ __launch_bounds__(64) void scan2_kernel(const int* __restrict__ bsums,
                                                   int* __restrict__ bofs, int NB) {
  int lane = threadIdx.x;
  int v = (lane < NB) ? bsums[lane] : 0;
  int inc = v;
  #pragma unroll
  for (int off = 1; off < 64; off <<= 1) {
    int u = __shfl_up(inc, off, 64);
    if (lane >= off) inc += u;
  }
  if (lane < NB) bofs[lane] = inc - v;
}

__global__ __launch_bounds__(256) void scan3_kernel(int* __restrict__ starts,
                                                    int* __restrict__ cursor,
                                                    const int* __restrict__ bofs) {
  int add = bofs[blockIdx.x];
  int idx = blockIdx.x * 256 + threadIdx.x;
  int4 s = ((int4*)starts)[idx];
  s.x += add; s.y += add; s.z += add; s.w += add;
  ((int4*)starts)[idx] = s;
  ((int4*)cursor)[idx] = s;
}

__global__ __launch_bounds__(256) void fill_kernel(
    const int* __restrict__ row, const int* __restrict__ col,
    const float* __restrict__ eattr,
    const float* __restrict__ mu1, const float* __restrict__ sg1,
    const float* __restrict__ mu2, const float* __restrict__ sg2,
    int* __restrict__ cursor, int* __restrict__ erow,
    uint4* __restrict__ ew1, uint4* __restrict__ ew2, int E) {
  int e = blockIdx.x * 256 + threadIdx.x;
  if (e >= E) return;
  int c = col[e];
  int pos = atomicAdd(&cursor[c], 1);
  float p0 = eattr[2 * e], p1 = eattr[2 * e + 1];
  float w1[8], w2[8];
  #pragma unroll
  for (int k = 0; k < 8; ++k) {
    float d0 = p0 - mu1[2 * k], d1 = p1 - mu1[2 * k + 1];
    float s0 = sg1[2 * k], s1 = sg1[2 * k + 1];
    w1[k] = __expf(-0.5f * (d0 * d0 / (1e-15f + s0 * s0) +
                            d1 * d1 / (1e-15f + s1 * s1)));
    float e0 = p0 - mu2[2 * k], e1 = p1 - mu2[2 * k + 1];
    float t0 = sg2[2 * k], t1 = sg2[2 * k + 1];
    w2[k] = __expf(-0.5f * (e0 * e0 / (1e-15f + t0 * t0) +
                            e1 * e1 / (1e-15f + t1 * t1)));
  }
  erow[pos] = row[e];
  ew1[pos] = make_uint4(packh2(w1[0], w1[1]), packh2(w1[2], w1[3]),
                        packh2(w1[4], w1[5]), packh2(w1[6], w1[7]));
  ew2[pos] = make_uint4(packh2(w2[0], w2[1]), packh2(w2[2], w2[3]),
                        packh2(w2[4], w2[5]), packh2(w2[6], w2[7]));
}

__global__ __launch_bounds__(256) void cast_x_kernel(const float* __restrict__ x,
                                                     ushort* __restrict__ A1, int N) {
  int idx = blockIdx.x * 256 + threadIdx.x;
  if (idx >= N * 32) return;
  int n = idx >> 5, c4 = idx & 31;
  float4 v = ((const float4*)x)[idx];
  ushort4 o;
  o.x = f2bu(v.x); o.y = f2bu(v.y); o.z = f2bu(v.z); o.w = f2bu(v.w);
  *(ushort4*)(A1 + (size_t)n * 1152 + 1024 + c4 * 4) = o;
}

// ---- prep: W1t [64][1152]; G2pT [144][64] permuted [g2w|r2w] (R8) ----
__global__ __launch_bounds__(256) void prep_kernel(
    const float* __restrict__ g1w, const float* __restrict__ r1w,
    const float* __restrict__ g2w, const float* __restrict__ r2w,
    ushort* __restrict__ W1t, ushort* __restrict__ G2pT) {
  int i = blockIdx.x * 256 + threadIdx.x;
  if (i < 64 * 1152) {
    int h = i / 1152, j = i % 1152;
    float v = (j < 1024) ? g1w[(size_t)(j & 127) * 512 + (j >> 7) * 64 + h]
                         : r1w[(size_t)(j - 1024) * 64 + h];
    W1t[i] = f2bu(v);
  } else {
    int i2 = i - 64 * 1152;
    if (i2 < 144 * 64) {
      int cp = i2 / 64, f = i2 % 64;
      float v;
      if (cp < 128) {
        int kq = cp >> 5, rem = cp & 31;
        int o = rem >> 1, k = kq * 2 + (rem & 1);
        v = g2w[(size_t)f * 128 + k * 16 + o];
      } else {
        v = r2w[(size_t)f * 16 + (cp - 128)];
      }
      G2pT[i2] = f2bu(v);
    }
  }
}

// ======= z1 v2: Z[n,k*128+f] = (1/deg) sum w_ek x_bf[r,f] =======
// Pre-scaled offsets, sentinels, split loops, depth-2 prefetch.
__global__ __launch_bounds__(256) void z1_kernel(
    ushort* __restrict__ A1, const int* __restrict__ erow,
    const uint4* __restrict__ ew1, const int* __restrict__ starts, int N) {
  __shared__ __align__(16) float lw[Z1CAP + 2][8];
  __shared__ int loff[Z1CAP + 2];
  const int t = threadIdx.x, lane = t & 63, wv = t >> 6;
  const int base = (int)blockIdx.x * Z1NODES;
  const int S = starts[base];
  const int cl = min(starts[base + Z1NODES] - S, Z1CAP);
  for (int i = t; i < cl; i += 256) {
    loff[i] = erow[S + i] * 2304;          // byte offset of row
    uint4 q = ew1[S + i];
    float2 a = unph2(q.x), b = unph2(q.y), c = unph2(q.z), d = unph2(q.w);
    *(float4*)&lw[i][0] = make_float4(a.x, a.y, b.x, b.y);
    *(float4*)&lw[i][4] = make_float4(c.x, c.y, d.x, d.y);
  }
  if (t < 2) {
    loff[cl + t] = 0;
    *(float4*)&lw[cl + t][0] = make_float4(0.f, 0.f, 0.f, 0.f);
    *(float4*)&lw[cl + t][4] = make_float4(0.f, 0.f, 0.f, 0.f);
  }
  __syncthreads();

  const char* xb = (const char*)(A1 + 1024) + (lane << 2);

  for (int i = 0; i < Z1NODES / 4; ++i) {
    const int n = base + wv * 4 + i;
    const int be = starts[n], ee = starts[n + 1];
    float a0[8], a1[8];
    #pragma unroll
    for (int k = 0; k < 8; ++k) { a0[k] = 0.f; a1[k] = 0.f; }

    const int re = min(ee, S + cl);        // end of LDS-window portion
    int j = be;
    if (j < re) {
      int rel = j - S;
      float4 wl0 = *(float4*)&lw[rel][0],     wh0 = *(float4*)&lw[rel][4];
      float4 wl1 = *(float4*)&lw[rel + 1][0], wh1 = *(float4*)&lw[rel + 1][4];
      uint g0 = *(const uint*)(xb + loff[rel]);
      uint g1 = *(const uint*)(xb + loff[rel + 1]);
      for (; j < re; ++j) {
        rel = j - S;
        float4 wl2 = *(float4*)&lw[rel + 2][0];
        float4 wh2 = *(float4*)&lw[rel + 2][4];
        uint g2 = *(const uint*)(xb + loff[rel + 2]);
        float f0 = __uint_as_float(g0 << 16);
        float f1 = __uint_as_float(g0 & 0xffff0000u);
        a0[0] = fmaf(wl0.x, f0, a0[0]); a1[0] = fmaf(wl0.x, f1, a1[0]);
        a0[1] = fmaf(wl0.y, f0, a0[1]); a1[1] = fmaf(wl0.y, f1, a1[1]);
        a0[2] = fmaf(wl0.z, f0, a0[2]); a1[2] = fmaf(wl0.z, f1, a1[2]);
        a0[3] = fmaf(wl0.w, f0, a0[3]); a1[3] = fmaf(wl0.w, f1, a1[3]);
        a0[4] = fmaf(wh0.x, f0, a0[4]); a1[4] = fmaf(wh0.x, f1, a1[4]);
        a0[5] = fmaf(wh0.y, f0, a0[5]); a1[5] = fmaf(wh0.y, f1, a1[5]);
        a0[6] = fmaf(wh0.z, f0, a0[6]); a1[6] = fmaf(wh0.z, f1, a1[6]);
        a0[7] = fmaf(wh0.w, f0, a0[7]); a1[7] = fmaf(wh0.w, f1, a1[7]);
        wl0 = wl1; wh0 = wh1; wl1 = wl2; wh1 = wh2; g0 = g1; g1 = g2;
      }
    }
    for (; j < ee; ++j) {                   // rare global tail
      uint4 q = ew1[j];
      uint g = *(const uint*)(xb + erow[j] * 2304);
      float2 a = unph2(q.x), b = unph2(q.y), c = unph2(q.z), d = unph2(q.w);
      float f0 = __uint_as_float(g << 16);
      float f1 = __uint_as_float(g & 0xffff0000u);
      a0[0] = fmaf(a.x, f0, a0[0]); a1[0] = fmaf(a.x, f1, a1[0]);
      a0[1] = fmaf(a.y, f0, a0[1]); a1[1] = fmaf(a.y, f1, a1[1]);
      a0[2] = fmaf(b.x, f0, a0[2]); a1[2] = fmaf(b.x, f1, a1[2]);
      a0[3] = fmaf(b.y, f0, a0[3]); a1[3] = fmaf(b.y, f1, a1[3]);
      a0[4] = fmaf(c.x, f0, a0[4]); a1[4] = fmaf(c.x, f1, a1[4]);
      a0[5] = fmaf(c.y, f0, a0[5]); a1[5] = fmaf(c.y, f1, a1[5]);
      a0[6] = fmaf(d.x, f0, a0[6]); a1[6] = fmaf(d.x, f1, a1[6]);
      a0[7] = fmaf(d.y, f0, a0[7]); a1[7] = fmaf(d.y, f1, a1[7]);
    }
    const float inv = 1.f / fmaxf((float)(ee - be), 1.f);
    ushort* zr = A1 + (size_t)n * 1152;
    #pragma unroll
    for (int k = 0; k < 8; ++k) {
      uint pk = (uint)f2bu(a0[k] * inv) | ((uint)f2bu(a1[k] * inv) << 16);
      *(uint*)(zr + k * 128 + 2 * lane) = pk;
    }
  }
}

// ---- gemm1 (unchanged R7/R8): h_bf = ELU( A1 @ W1t^T + b1 ), LDS-dbuf ----
__global__ __launch_bounds__(256) void gemm1_mfma(
    const ushort* __restrict__ A1, const ushort* __restrict__ W1t,
    const float* __restrict__ b1, ushort* __restrict__ h_bf, int N) {
  __shared__ __align__(16) ushort As[2][64 * 32];
  __shared__ __align__(16) ushort Bs[2][64 * 32];
  const int t = threadIdx.x, lane = t & 63, wv = t >> 6;
  const int mfrag = lane & 15, quad = lane >> 4;
  const int m0 = (int)blockIdx.x * 64;
  const int st_r = t >> 2, st_c = (t & 3) * 8;
  const int st_o = st_r * 32 + st_c;
  const ushort* ag = A1 + (size_t)(m0 + st_r) * 1152 + st_c;
  const ushort* bg = W1t + (size_t)st_r * 1152 + st_c;

  {
    uint4 a0 = *(const uint4*)ag;
    uint4 b0 = *(const uint4*)bg;
    *(uint4*)(&As[0][st_o]) = a0;
    *(uint4*)(&Bs[0][st_o]) = b0;
  }
  __syncthreads();

  v4f acc[4];
  #pragma unroll
  for (int ct = 0; ct < 4; ++ct) acc[ct] = (v4f){0.f, 0.f, 0.f, 0.f};

  for (int kc = 0; kc < 36; ++kc) {
    const int cb = kc & 1, nb = cb ^ 1;
    uint4 an, bn;
    if (kc < 35) {
      an = *(const uint4*)(ag + (kc + 1) * 32);
      bn = *(const uint4*)(bg + (kc + 1) * 32);
    }
    v8bf a = ld_frag(&As[cb][(wv * 16 + mfrag) * 32 + quad * 8]);
    #pragma unroll
    for (int ct = 0; ct < 4; ++ct) {
      v8bf b = ld_frag(&Bs[cb][(ct * 16 + mfrag) * 32 + quad * 8]);
      acc[ct] = __builtin_amdgcn_mfma_f32_16x16x32_bf16(a, b, acc[ct], 0, 0, 0);
    }
    if (kc < 35) {
      *(uint4*)(&As[nb][st_o]) = an;
      *(uint4*)(&Bs[nb][st_o]) = bn;
      __syncthreads();
    }
  }
  #pragma unroll
  for (int ct = 0; ct < 4; ++ct) {
    const int colh = ct * 16 + mfrag;
    const float bc = b1[colh];
    #pragma unroll
    for (int r = 0; r < 4; ++r) {
      int node = m0 + wv * 16 + quad * 4 + r;
      if (node < N) {
        float v = acc[ct][r] + bc;
        v = v > 0.f ? v : expm1f(v);
        h_bf[(size_t)node * NH + colh] = f2bu(v);
      }
    }
  }
}

// ---- gemm2a (unchanged R8): gx2e[N,160] = bf16( h_bf @ G2pT^T ) ----
__global__ __launch_bounds__(256) void gemm2a_kernel(
    const ushort* __restrict__ h_bf, const ushort* __restrict__ G2pT,
    ushort* __restrict__ gx2e, int N) {
  const int t = threadIdx.x, lane = t & 63, wv = t >> 6;
  const int mfrag = lane & 15, quad = lane >> 4;
  const int m0 = (int)blockIdx.x * 64 + wv * 16;
  v4f acc[9];
  #pragma unroll
  for (int t9 = 0; t9 < 9; ++t9) acc[t9] = (v4f){0.f, 0.f, 0.f, 0.f};
  const ushort* arow = h_bf + (size_t)(m0 + mfrag) * 64 + quad * 8;
  const ushort* brow = G2pT + (size_t)mfrag * 64 + quad * 8;
  #pragma unroll
  for (int kc = 0; kc < 2; ++kc) {
    v8bf a = ld_frag(arow + kc * 32);
    #pragma unroll
    for (int t9 = 0; t9 < 9; ++t9) {
      v8bf b = ld_frag(brow + (size_t)t9 * 16 * 64 + kc * 32);
      acc[t9] = __builtin_amdgcn_mfma_f32_16x16x32_bf16(a, b, acc[t9], 0, 0, 0);
    }
  }
  #pragma unroll
  for (int t9 = 0; t9 < 9; ++t9) {
    #pragma unroll
    for (int r = 0; r < 4; ++r) {
      int node = m0 + quad * 4 + r;
      if (node < N)
        gx2e[(size_t)node * GXST + t9 * 16 + mfrag] = f2bu(acc[t9][r]);
    }
  }
}

// ==== edge2 v2: out = lsm( (sum_e w.gx2e[r])/deg + root + b2 ) ====
__global__ __launch_bounds__(256) void edge2_kernel(
    const ushort* __restrict__ gx2e, const int* __restrict__ erow,
    const uint4* __restrict__ ew2, const int* __restrict__ starts,
    const float* __restrict__ b2, float* __restrict__ out, int N) {
  __shared__ __align__(16) float lw[E2CAP + 2][8];
  __shared__ int loff[E2CAP + 2];
  __shared__ float lb2[16];
  const int t = threadIdx.x, lane = t & 63, wv = t >> 6;
  const int base = (int)blockIdx.x * E2NODES;
  const int S = starts[base];
  const int cl = min(starts[base + E2NODES] - S, E2CAP);
  if (t < 16) lb2[t] = b2[t];
  for (int i = t; i < cl; i += 256) {
    loff[i] = erow[S + i] * 320;
    uint4 q = ew2[S + i];
    float2 a = unph2(q.x), b = unph2(q.y), c = unph2(q.z), d = unph2(q.w);
    *(float4*)&lw[i][0] = make_float4(a.x, a.y, b.x, b.y);
    *(float4*)&lw[i][4] = make_float4(c.x, c.y, d.x, d.y);
  }
  if (t < 2) {
    loff[cl + t] = 0;
    *(float4*)&lw[cl + t][0] = make_float4(0.f, 0.f, 0.f, 0.f);
    *(float4*)&lw[cl + t][4] = make_float4(0.f, 0.f, 0.f, 0.f);
  }
  __syncthreads();

  const int o = lane & 15, kq = lane >> 4;
  const char* gb = (const char*)gx2e + kq * 64 + o * 4;

  for (int i = 0; i < E2NODES / 4; ++i) {
    const int n = base + wv * 4 + i;
    if (n >= N) continue;
    const int be = starts[n], ee = starts[n + 1];
    float acc0 = 0.f, acc1 = 0.f;
    const int re = min(ee, S + cl);
    int j = be;
    if (j < re) {
      int rel = j - S;
      float2 w0 = *(float2*)&lw[rel][kq * 2];
      float2 w1 = *(float2*)&lw[rel + 1][kq * 2];
      uint g0 = *(const uint*)(gb + loff[rel]);
      uint g1 = *(const uint*)(gb + loff[rel + 1]);
      for (; j < re; ++j) {
        rel = j - S;
        float2 w2 = *(float2*)&lw[rel + 2][kq * 2];
        uint g2 = *(const uint*)(gb + loff[rel + 2]);
        float f0 = __uint_as_float(g0 << 16);
        float f1 = __uint_as_float(g0 & 0xffff0000u);
        acc0 = fmaf(w0.x, f0, acc0);
        acc1 = fmaf(w0.y, f1, acc1);
        w0 = w1; w1 = w2; g0 = g1; g1 = g2;
      }
    }
    for (; j < ee; ++j) {                   // rare global tail
      uint4 q = ew2[j];
      uint comp = (kq == 0) ? q.x : (kq == 1) ? q.y : (kq == 2) ? q.z : q.w;
      float2 wp = unph2(comp);
      uint g = *(const uint*)(gb + erow[j] * 320);
      float f0 = __uint_as_float(g << 16);
      float f1 = __uint_as_float(g & 0xffff0000u);
      acc0 = fmaf(wp.x, f0, acc0);
      acc1 = fmaf(wp.y, f1, acc1);
    }
    float s = acc0 + acc1;
    s += __shfl_xor(s, 16, 64);
    s += __shfl_xor(s, 32, 64);
    const float inv = 1.f / fmaxf((float)(ee - be), 1.f);
    ushort ru = *((const ushort*)gx2e + (size_t)n * GXST + 128 + o);
    float root = __uint_as_float(((uint)ru) << 16);
    float v = s * inv + root + lb2[o];
    float mx = v;
    #pragma unroll
    for (int off = 8; off >= 1; off >>= 1) mx = fmaxf(mx, __shfl_xor(mx, off, 64));
    float sm = __expf(v - mx);
    #pragma unroll
    for (int off = 8; off >= 1; off >>= 1) sm += __shfl_xor(sm, off, 64);
    if (kq == 0) out[(size_t)n * NC + o] = v - mx - __logf(sm);
  }
}

extern "C" void kernel_launch(void* const* d_in, const int* in_sizes, int n_in,
                              void* d_out, int out_size, void* d_ws, size_t ws_size,
                              hipStream_t stream) {
  const float* x     = (const float*)d_in[0];
  const int*   eidx  = (const int*)d_in[1];
  const float* eattr = (const float*)d_in[2];
  const float* g1w   = (const float*)d_in[3];
  const float* mu1   = (const float*)d_in[4];
  const float* sg1   = (const float*)d_in[5];
  const float* r1w   = (const float*)d_in[6];
  const float* b1    = (const float*)d_in[7];
  const float* g2w   = (const float*)d_in[8];
  const float* mu2   = (const float*)d_in[9];
  const float* sg2   = (const float*)d_in[10];
  const float* r2w   = (const float*)d_in[11];
  const float* b2    = (const float*)d_in[12];

  const int N = in_sizes[0] / NF;        // 50000
  const int E = in_sizes[1] / 2;         // 800000
  const int* row = eidx;
  const int* col = eidx + E;
  const int N2 = (N + 63) & ~63;         // 50048
  const int NP = (N + 1023) & ~1023;     // 50176
  const int NB = NP / 1024;              // 49

  uint4* ew1   = (uint4*)d_ws;                         // E
  uint4* ew2   = ew1 + (size_t)E;                      // E
  ushort* A1   = (ushort*)(ew2 + (size_t)E);           // N2*1152 (Z1|x)
  ushort* gx2e = A1;                                   // [N2,160] after gemm1
  ushort* h_bf = A1 + (size_t)N2 * 1152;               // N2*64
  ushort* W1t  = h_bf + (size_t)N2 * NH;               // 64*1152
  ushort* G2pT = W1t + (size_t)64 * 1152;              // 144*64
  int* erow    = (int*)(G2pT + (size_t)144 * 64);      // E
  int* counts  = erow + (size_t)E;                     // NP
  int* starts  = counts + NP;                          // NP
  int* cursor  = starts + NP;                          // NP
  int* bsums   = cursor + NP;                          // 64
  int* bofs    = bsums + 64;                           // 64

  hipMemsetAsync(counts, 0, (size_t)NP * sizeof(int), stream);
  hist_kernel<<<(E + 255) / 256, 256, 0, stream>>>(col, counts, E);
  scan1_kernel<<<NB, 256, 0, stream>>>(counts, starts, bsums);
  scan2_kernel<<<1, 64, 0, stream>>>(bsums, bofs, NB);
  scan3_kernel<<<NB, 256, 0, stream>>>(starts, cursor, bofs);
  fill_kernel<<<(E + 255) / 256, 256, 0, stream>>>(row, col, eattr, mu1, sg1,
                                                   mu2, sg2, cursor, erow,
                                                   ew1, ew2, E);
  cast_x_kernel<<<(N * 32 + 255) / 256, 256, 0, stream>>>(x, A1, N);
  prep_kernel<<<(64 * 1152 + 144 * 64 + 255) / 256, 256, 0, stream>>>(
      g1w, r1w, g2w, r2w, W1t, G2pT);

  z1_kernel<<<N / Z1NODES, 256, 0, stream>>>(A1, erow, ew1, starts, N);
  gemm1_mfma<<<N2 / 64, 256, 0, stream>>>(A1, W1t, b1, h_bf, N);
  gemm2a_kernel<<<N2 / 64, 256, 0, stream>>>(h_bf, G2pT, gx2e, N);
  edge2_kernel<<<(N + E2NODES - 1) / E2NODES, 256, 0, stream>>>(
      gx2e, erow, ew2, starts, b2, (float*)d_out, N);
}